// Round 5
// baseline (188.718 us; speedup 1.0000x reference)
//
#include <hip/hip_runtime.h>

#define Lc 1024
#define Dc 512
#define Hc 8
#define DHc 64

typedef __attribute__((ext_vector_type(8))) short bf16x8;
typedef __attribute__((ext_vector_type(4))) float f32x4;

typedef __attribute__((address_space(1))) const unsigned int guint;
typedef __attribute__((address_space(3))) unsigned int luint;

__device__ __forceinline__ void gload_lds16(const void* g, void* l) {
    __builtin_amdgcn_global_load_lds((guint*)g, (luint*)l, 16, 0, 0);
}

__device__ __forceinline__ unsigned short f2bf(float f) {
    unsigned u = __float_as_uint(f);
    u += 0x7fffu + ((u >> 16) & 1u);          // round-to-nearest-even
    return (unsigned short)(u >> 16);
}
__device__ __forceinline__ unsigned pk2(float a, float b) {
    return (unsigned)f2bf(a) | ((unsigned)f2bf(b) << 16);
}
__device__ __forceinline__ unsigned pk2t(float a, float b) {   // truncating pack, 1 v_perm
    return __builtin_amdgcn_perm(__float_as_uint(b), __float_as_uint(a), 0x07060302u);
}
__device__ __forceinline__ float bf2f(unsigned short s) { return __uint_as_float(((unsigned)s) << 16); }

// ---------------------------------------------------------------------------
// fp32 -> bf16 cast of x, Wq, Wk, Wv, Wo, We
// ---------------------------------------------------------------------------
__global__ void cvt_all_kernel(
    const float* __restrict__ x,  const float* __restrict__ Wq,
    const float* __restrict__ Wk, const float* __restrict__ Wv,
    const float* __restrict__ Wo, const float* __restrict__ We,
    unsigned short* __restrict__ xb,  unsigned short* __restrict__ wqb,
    unsigned short* __restrict__ wkb, unsigned short* __restrict__ wvb,
    unsigned short* __restrict__ wob, unsigned short* __restrict__ wet)
{
    int bid = blockIdx.x;
    const float* src; unsigned short* dst; size_t base;
    if      (bid < 4096) { src = x;  dst = xb;  base = (size_t)bid * 1024; }
    else if (bid < 4352) { src = Wq; dst = wqb; base = (size_t)(bid-4096) * 1024; }
    else if (bid < 4608) { src = Wk; dst = wkb; base = (size_t)(bid-4352) * 1024; }
    else if (bid < 4864) { src = Wv; dst = wvb; base = (size_t)(bid-4608) * 1024; }
    else if (bid < 5120) { src = Wo; dst = wob; base = (size_t)(bid-4864) * 1024; }
    else                 { src = We; dst = wet; base = (size_t)(bid-5120) * 1024; }
    size_t i = base + (size_t)threadIdx.x * 4;
    float4 a = *(const float4*)&src[i];
    *(uint2*)&dst[i] = make_uint2(pk2(a.x, a.y), pk2(a.z, a.w));
}

// ---------------------------------------------------------------------------
// QKV projection, bf16 MFMA, BK=64, full-DMA staging (R6-proven config).
// ---------------------------------------------------------------------------
__global__ __launch_bounds__(256, 3) void proj_mfma_kernel(
    const unsigned short* __restrict__ xb,
    const unsigned short* __restrict__ wq, const unsigned short* __restrict__ wk,
    const unsigned short* __restrict__ wv,
    unsigned short* __restrict__ qo, unsigned short* __restrict__ ko,
    unsigned short* __restrict__ vtg, float qscale)
{
    const unsigned short* W;
    if (blockIdx.z == 0)      W = wq;
    else if (blockIdx.z == 1) W = wk;
    else                      W = wv;

    __shared__ unsigned short smem[128 * 136];      // As(8192) Bs(8192) / Ts(17408)
    unsigned short* As = smem;
    unsigned short* Bs = smem + 8192;

    const int t = threadIdx.x;
    const int lane = t & 63, w = t >> 6;
    const int lq = lane >> 4, ln = lane & 15;
    const int m0 = blockIdx.y * 128, n0 = blockIdx.x * 128;
    const int wm = (w & 1) * 64, wn = (w >> 1) * 64;
    const int srow = t >> 3;                        // 0..31
    const int lsg  = ((t & 7) ^ ((t >> 3) & 7)) * 8;  // swizzled source seg*8
    const int key  = ln & 7;

    f32x4 acc[4][4];
    #pragma unroll
    for (int i = 0; i < 4; i++)
        #pragma unroll
        for (int j = 0; j < 4; j++) acc[i][j] = (f32x4){0.f,0.f,0.f,0.f};

    for (int c0 = 0; c0 < 512; c0 += 64) {
        __syncthreads();
        #pragma unroll
        for (int g = 0; g < 4; g++) {
            gload_lds16(&xb[(size_t)(m0 + 32*g + srow) * 512 + c0 + lsg], &As[(32*g + srow)*64 + (t&7)*8]);
            gload_lds16(&W [(size_t)(n0 + 32*g + srow) * 512 + c0 + lsg], &Bs[(32*g + srow)*64 + (t&7)*8]);
        }
        __syncthreads();

        #pragma unroll
        for (int kk = 0; kk < 2; kk++) {
            bf16x8 af[4], bf[4];
            #pragma unroll
            for (int i = 0; i < 4; i++)
                af[i] = *(bf16x8*)&As[(wm + 16*i + ln)*64 + ((kk*4 + lq) ^ key)*8];
            #pragma unroll
            for (int j = 0; j < 4; j++)
                bf[j] = *(bf16x8*)&Bs[(wn + 16*j + ln)*64 + ((kk*4 + lq) ^ key)*8];
            #pragma unroll
            for (int i = 0; i < 4; i++)
                #pragma unroll
                for (int j = 0; j < 4; j++)
                    acc[i][j] = __builtin_amdgcn_mfma_f32_16x16x32_bf16(af[i], bf[j], acc[i][j], 0, 0, 0);
        }
    }

    if (blockIdx.z < 2) {
        unsigned short* out = (blockIdx.z == 0) ? qo : ko;
        const float osc = (blockIdx.z == 0) ? qscale : 1.0f;
        #pragma unroll
        for (int i = 0; i < 4; i++) {
            #pragma unroll
            for (int r = 0; r < 4; r++) {
                int m = m0 + wm + 16*i + 4*lq + r;
                int b = m >> 10, l = m & 1023;
                #pragma unroll
                for (int j = 0; j < 4; j++) {
                    int n = n0 + wn + 16*j + ln;
                    int h = n >> 6, dh = n & 63;
                    out[((size_t)((b*Hc + h)*Lc + l))*DHc + dh] = f2bf(acc[i][j][r] * osc);
                }
            }
        }
    } else {
        // V: transpose through LDS, write V^T (B,H,DH,L)
        __syncthreads();
        unsigned short* Ts = smem;      // [n_local][m_local] stride 136
        #pragma unroll
        for (int i = 0; i < 4; i++) {
            int mlb = wm + 16*i + 4*lq;
            #pragma unroll
            for (int j = 0; j < 4; j++) {
                int nl = wn + 16*j + ln;
                *(uint2*)&Ts[nl*136 + mlb] = make_uint2(pk2(acc[i][j][0], acc[i][j][1]),
                                                        pk2(acc[i][j][2], acc[i][j][3]));
            }
        }
        __syncthreads();
        const int b = m0 >> 10, l0m = m0 & 1023;
        const int nl = t >> 1, seg = (t & 1) * 64;
        const int ng = n0 + nl, h = ng >> 6, dh = ng & 63;
        unsigned short* dst = vtg + (((size_t)(b*Hc + h))*DHc + dh)*Lc + l0m + seg;
        #pragma unroll
        for (int u = 0; u < 8; u++)
            *(uint4*)&dst[8*u] = *(uint4*)&Ts[nl*136 + seg + 8*u];
    }
}

// ---------------------------------------------------------------------------
// Output GEMM, bf16 MFMA, 64x64 tiles (1024 blocks = 4/CU). BK=64, swizzled
// DMA. out = awb @ Wo^T + bo (fp32 out).
// ---------------------------------------------------------------------------
__global__ __launch_bounds__(256, 4) void out_mfma_kernel(
    const unsigned short* __restrict__ A, const unsigned short* __restrict__ W,
    const float* __restrict__ bias, float* __restrict__ out)
{
    __shared__ unsigned short As[64 * 64];
    __shared__ unsigned short Bs[64 * 64];

    const int t = threadIdx.x;
    const int lane = t & 63, w = t >> 6;
    const int lq = lane >> 4, ln = lane & 15;
    const int m0 = blockIdx.y * 64, n0 = blockIdx.x * 64;
    const int wm = (w & 1) * 32, wn = (w >> 1) * 32;
    const int srow = t >> 3;                        // 0..31
    const int lsg  = ((t & 7) ^ ((t >> 3) & 7)) * 8;
    const int key  = ln & 7;

    f32x4 acc[2][2];
    #pragma unroll
    for (int i = 0; i < 2; i++)
        #pragma unroll
        for (int j = 0; j < 2; j++) acc[i][j] = (f32x4){0.f,0.f,0.f,0.f};

    for (int c0 = 0; c0 < 512; c0 += 64) {
        __syncthreads();
        #pragma unroll
        for (int g = 0; g < 2; g++) {
            gload_lds16(&A[(size_t)(m0 + 32*g + srow) * 512 + c0 + lsg], &As[(32*g + srow)*64 + (t&7)*8]);
            gload_lds16(&W[(size_t)(n0 + 32*g + srow) * 512 + c0 + lsg], &Bs[(32*g + srow)*64 + (t&7)*8]);
        }
        __syncthreads();

        #pragma unroll
        for (int kk = 0; kk < 2; kk++) {
            bf16x8 af[2], bf[2];
            #pragma unroll
            for (int i = 0; i < 2; i++)
                af[i] = *(bf16x8*)&As[(wm + 16*i + ln)*64 + ((kk*4 + lq) ^ key)*8];
            #pragma unroll
            for (int j = 0; j < 2; j++)
                bf[j] = *(bf16x8*)&Bs[(wn + 16*j + ln)*64 + ((kk*4 + lq) ^ key)*8];
            #pragma unroll
            for (int i = 0; i < 2; i++)
                #pragma unroll
                for (int j = 0; j < 2; j++)
                    acc[i][j] = __builtin_amdgcn_mfma_f32_16x16x32_bf16(af[i], bf[j], acc[i][j], 0, 0, 0);
        }
    }

    float bb[2];
    #pragma unroll
    for (int j = 0; j < 2; j++) bb[j] = bias[n0 + wn + 16*j + ln];

    #pragma unroll
    for (int i = 0; i < 2; i++) {
        #pragma unroll
        for (int r = 0; r < 4; r++) {
            int m = m0 + wm + 16*i + 4*lq + r;
            #pragma unroll
            for (int j = 0; j < 2; j++) {
                int n = n0 + wn + 16*j + ln;
                out[(size_t)m * Dc + n] = acc[i][j][r] + bb[j];
            }
        }
    }
}

// ---------------------------------------------------------------------------
// attn v10: v9 orientation (S^T/O^T, packed P) + K and We moved OFF the LDS
// pipe to register-direct global loads WITH latency slack (the v8 lesson):
//   We: ping-pong prefetch (issued iter i, consumed at QE of iter i+1)
//   K : single-buffer, issued top-of-iter, consumed at QK (behind QE + bar)
//   V : stays DMA->LDS (B-operand shared by 2 waves; keeps VGPR <= 128)
// Removes 8 of 16 b128 reads + 4 of 6 DMA writes per wave-iter (-35% LDS);
// barriers 4 -> 3 (ps2 no longer aliased). LDS 40960 -> 32768 B.
// ---------------------------------------------------------------------------
__global__ __launch_bounds__(256, 4) void attn_v10_kernel(
    const unsigned short* __restrict__ q, const unsigned short* __restrict__ k,
    const unsigned short* __restrict__ vtg, const unsigned short* __restrict__ wet,
    unsigned short* __restrict__ attn)
{
    __shared__ unsigned short vtp [2 * 64 * 32];    // 8192  V^T planes [kk][dh][32]
    __shared__ unsigned short ps2 [64 * 64];        // 8192  P^T exchange [l][s-swz]
    __shared__ unsigned short qes [128 * 64];       // 16384 QE ring [slot][col^swz]
    // total 32768 B -> 4 blocks/CU

    const int t    = threadIdx.x;
    const int lane = t & 63, w = t >> 6;
    const int lq   = lane >> 4, ln = lane & 15;
    const int si   = w >> 1;                        // s / dh half: 0/1
    const int li   = w & 1;                         // l half: 0/1

    const int n   = blockIdx.x;
    const int xcd = n & 7, idx = n >> 3;
    const int bh  = xcd * 8 + (idx >> 4);
    const int l0  = (idx & 15) * 64;

    const unsigned short* qb  = q   + (size_t)bh * (Lc * DHc);
    const unsigned short* kb  = k   + (size_t)bh * (Lc * DHc);
    const unsigned short* vtb = vtg + (size_t)bh * (DHc * Lc);

    const int trow = t >> 2;
    const int sseg = ((t & 3) ^ ((t >> 4) & 3)) * 8;
    const int swz  = (ln >> 2) & 3;

    const bf16x8 onesf = {(short)0x3F80,(short)0x3F80,(short)0x3F80,(short)0x3F80,
                          (short)0x3F80,(short)0x3F80,(short)0x3F80,(short)0x3F80};

    // Q fragments: lane ln <-> l = l0 + 32*li + 16*lt + ln; lq <-> dh chunk
    bf16x8 qf[2][2];
    #pragma unroll
    for (int lt = 0; lt < 2; lt++)
        #pragma unroll
        for (int kk = 0; kk < 2; kk++)
            qf[lt][kk] = *(const bf16x8*)&qb[(size_t)(l0 + 32*li + 16*lt + ln)*64 + kk*32 + lq*8];

    const int pb0 = 15 - (l0 >> 6);

    // prologue: cold We panel pb0 + iter-0 We prefetch (panel pb0+1)
    bf16x8 wA[2][2], wB[2][2];
    bf16x8 wpre[2][2];
    #pragma unroll
    for (int kk = 0; kk < 2; kk++)
        #pragma unroll
        for (int et = 0; et < 2; et++) {
            const size_t ro = (size_t)(16*(2*si+et) + ln)*64 + kk*32 + lq*8;
            wpre[kk][et] = *(const bf16x8*)&wet[(size_t)(64*pb0    )*64 + ro];
            wA  [kk][et] = *(const bf16x8*)&wet[(size_t)(64*(pb0+1))*64 + ro];  // iter0 panel (pad-safe at 16)
        }

    // pre-loop QE panel pb0 -> ring
    {
        f32x4 qec[2][2];
        #pragma unroll
        for (int lt = 0; lt < 2; lt++)
            #pragma unroll
            for (int et = 0; et < 2; et++) qec[lt][et] = (f32x4){0.f,0.f,0.f,0.f};
        #pragma unroll
        for (int kk = 0; kk < 2; kk++)
            #pragma unroll
            for (int et = 0; et < 2; et++)
                #pragma unroll
                for (int lt = 0; lt < 2; lt++)
                    qec[lt][et] = __builtin_amdgcn_mfma_f32_16x16x32_bf16(qf[lt][kk], wpre[kk][et], qec[lt][et], 0, 0, 0);
        const int cb = (pb0 & 1) * 64;
        #pragma unroll
        for (int et = 0; et < 2; et++) {
            const int row = cb + 16*(2*si+et) + ln;               // (row&15) == e&15
            #pragma unroll
            for (int lt = 0; lt < 2; lt++)
                *(uint2*)&qes[row*64 + ((32*li + 16*lt + 4*lq) ^ (ln << 2))] =
                    make_uint2(pk2(qec[lt][et][0], qec[lt][et][1]),
                               pk2(qec[lt][et][2], qec[lt][et][3]));
        }
    }

    f32x4 Lacc[2];
    f32x4 Ov[2][2];                                 // [dt][lt]
    #pragma unroll
    for (int lt = 0; lt < 2; lt++) {
        Lacc[lt] = (f32x4){0.f,0.f,0.f,0.f};
        #pragma unroll
        for (int dt = 0; dt < 2; dt++) Ov[dt][lt] = (f32x4){0.f,0.f,0.f,0.f};
    }

    int pbOld = pb0 - 1;

    auto body = [&](int s0, bf16x8 (&wcur)[2][2], bf16x8 (&wnxt)[2][2]) {
        const int c0  = l0 - s0;
        const int ac0 = c0 < 0 ? -c0 : c0;
        const int pb  = (960 - ac0) >> 6;
        const int newp = (pb > pbOld) ? pb + 1 : pb;
        pbOld = pb;
        const int cb = (newp & 1) * 64;

        // next-iter prefetch indices (clamped into valid/pad memory; values
        // past the end are never consumed)
        const int nc0  = c0 - 64;
        const int nac0 = nc0 < 0 ? -nc0 : nc0;
        int npb = (960 - nac0) >> 6;
        int nnp = (npb > pb) ? npb + 1 : npb;
        if (nnp < 0) nnp = 0;
        const int ns0 = s0 + 64;                    // 1024 on last iter: reads
                                                    // spill into next ws region (safe, unused)

        __syncthreads();                            // bar1: prev PV done with ps2/vtp

        // V DMA for this iter (consumed after bar2)
        gload_lds16(&vtb[(size_t)trow*1024 + s0 +      sseg], &vtp[t*8]);
        gload_lds16(&vtb[(size_t)trow*1024 + s0 + 32 + sseg], &vtp[2048 + t*8]);

        // K for THIS iter (consumed at QK, behind QE + bar2 -> latency hidden)
        bf16x8 kcur[2][2];
        #pragma unroll
        for (int kk = 0; kk < 2; kk++)
            #pragma unroll
            for (int st = 0; st < 2; st++)
                kcur[kk][st] = *(const bf16x8*)&kb[(size_t)(ns0 - 64 + 32*si + 16*st + ln)*64 + kk*32 + lq*8];
        // We for NEXT iter (full-iteration slack)
        #pragma unroll
        for (int kk = 0; kk < 2; kk++)
            #pragma unroll
            for (int et = 0; et < 2; et++)
                wnxt[kk][et] = *(const bf16x8*)&wet[(size_t)(64*nnp + 16*(2*si+et) + ln)*64 + kk*32 + lq*8];

        // ---- QE: panel newp (register operands) -> ring ----
        {
            f32x4 qec[2][2];
            #pragma unroll
            for (int lt = 0; lt < 2; lt++)
                #pragma unroll
                for (int et = 0; et < 2; et++) qec[lt][et] = (f32x4){0.f,0.f,0.f,0.f};
            #pragma unroll
            for (int kk = 0; kk < 2; kk++)
                #pragma unroll
                for (int et = 0; et < 2; et++)
                    #pragma unroll
                    for (int lt = 0; lt < 2; lt++)
                        qec[lt][et] = __builtin_amdgcn_mfma_f32_16x16x32_bf16(qf[lt][kk], wcur[kk][et], qec[lt][et], 0, 0, 0);
            #pragma unroll
            for (int et = 0; et < 2; et++) {
                const int row = cb + 16*(2*si+et) + ln;
                #pragma unroll
                for (int lt = 0; lt < 2; lt++)
                    *(uint2*)&qes[row*64 + ((32*li + 16*lt + 4*lq) ^ (ln << 2))] =
                        make_uint2(pk2(qec[lt][et][0], qec[lt][et][1]),
                                   pk2(qec[lt][et][2], qec[lt][et][3]));
            }
        }

        __syncthreads();                            // bar2: ring visible; vtp ready
                                                    // (also drains kcur/wnxt loads)

        // ---- S^T = mfma(K, Q): rows s = 32si+16st+4lq+r, cols l ----
        f32x4 sc[2][2];                             // [st][lt]
        #pragma unroll
        for (int st = 0; st < 2; st++)
            #pragma unroll
            for (int lt = 0; lt < 2; lt++) sc[st][lt] = (f32x4){0.f,0.f,0.f,0.f};
        #pragma unroll
        for (int kk = 0; kk < 2; kk++)
            #pragma unroll
            for (int st = 0; st < 2; st++)
                #pragma unroll
                for (int lt = 0; lt < 2; lt++)
                    sc[st][lt] = __builtin_amdgcn_mfma_f32_16x16x32_bf16(kcur[kk][st], qf[lt][kk], sc[st][lt], 0, 0, 0);

        // ---- bias + exp2 + packed P^T write ----
        #pragma unroll
        for (int st = 0; st < 2; st++)
            #pragma unroll
            for (int lt = 0; lt < 2; lt++) {
                const int lloc = 32*li + 16*lt + ln;
                const int sb   = 32*si + 16*st + 4*lq;
                float p[4];
                #pragma unroll
                for (int r = 0; r < 4; r++) {
                    int d  = c0 + lloc - (sb + r);
                    int ad = d < 0 ? -d : d;
                    int m  = 1023 - ad;
                    float bias = bf2f(qes[(m & 127)*64 + (lloc ^ ((m & 15) << 2))]);
                    p[r] = __builtin_amdgcn_exp2f(sc[st][lt][r] + bias);
                }
                const int blk = (4*si + 2*st + (lq >> 1)) ^ (ln & 7);   // lloc&7 == ln&7
                *(uint2*)&ps2[lloc*64 + blk*8 + (lq & 1)*4] =
                    make_uint2(pk2t(p[0], p[1]), pk2t(p[2], p[3]));
            }

        __syncthreads();                            // bar3: P visible

        // ---- O^T = mfma(V^T, P^T): rows dh = 32si+16dt+4lq+r, cols l ----
        #pragma unroll
        for (int kk = 0; kk < 2; kk++) {
            bf16x8 pf[2];
            #pragma unroll
            for (int lt = 0; lt < 2; lt++) {
                const int row = 32*li + 16*lt + ln;
                pf[lt] = *(bf16x8*)&ps2[row*64 + ((4*kk + lq) ^ (ln & 7))*8];
            }
            #pragma unroll
            for (int lt = 0; lt < 2; lt++)
                Lacc[lt] = __builtin_amdgcn_mfma_f32_16x16x32_bf16(onesf, pf[lt], Lacc[lt], 0, 0, 0);
            #pragma unroll
            for (int dt = 0; dt < 2; dt++) {
                bf16x8 vf = *(bf16x8*)&vtp[kk*2048 + (32*si + 16*dt + ln)*32 + (lq ^ swz)*8];
                #pragma unroll
                for (int lt = 0; lt < 2; lt++)
                    Ov[dt][lt] = __builtin_amdgcn_mfma_f32_16x16x32_bf16(vf, pf[lt], Ov[dt][lt], 0, 0, 0);
            }
        }
    };

    #pragma unroll 1
    for (int s0 = 0; s0 < Lc; s0 += 128) {
        body(s0,      wA, wB);
        body(s0 + 64, wB, wA);
    }

    const int b = bh >> 3, h = bh & 7;
    #pragma unroll
    for (int lt = 0; lt < 2; lt++) {
        const float inv = 1.f / Lacc[lt][0];        // all 4 rows identical
        const int l = l0 + 32*li + 16*lt + ln;
        unsigned short* dst = &attn[((size_t)(b*Lc + l))*Dc + h*DHc];
        #pragma unroll
        for (int dt = 0; dt < 2; dt++) {
            const int dh = 32*si + 16*dt + 4*lq;
            *(uint2*)&dst[dh] = make_uint2(pk2(Ov[dt][lt][0]*inv, Ov[dt][lt][1]*inv),
                                           pk2(Ov[dt][lt][2]*inv, Ov[dt][lt][3]*inv));
        }
    }
}

extern "C" void kernel_launch(void* const* d_in, const int* in_sizes, int n_in,
                              void* d_out, int out_size, void* d_ws, size_t ws_size,
                              hipStream_t stream)
{
    (void)in_sizes; (void)n_in; (void)out_size; (void)ws_size;
    const float* x  = (const float*)d_in[0];
    const float* Wq = (const float*)d_in[1];
    const float* Wk = (const float*)d_in[2];
    const float* Wv = (const float*)d_in[3];
    const float* We = (const float*)d_in[4];
    const float* Wo = (const float*)d_in[5];
    const float* bo = (const float*)d_in[6];

    const size_t NT = (size_t)8 * Hc * Lc * DHc;     // 4,194,304 elems
    unsigned short* qw  = (unsigned short*)d_ws;
    unsigned short* kw  = qw  + NT;
    unsigned short* vtg = kw  + NT;                  // V^T (B,H,DH,L)
    unsigned short* xbf = vtg + NT;
    unsigned short* awb = xbf + NT;                  // attn out bf16 (B,L,D)
    unsigned short* wqb = awb + NT;
    unsigned short* wkb = wqb + 262144;
    unsigned short* wvb = wkb + 262144;
    unsigned short* wob = wvb + 262144;
    unsigned short* wet = wob + 262144;              // 65536 + 4096 pad (panel-16 overread)

    cvt_all_kernel<<<5184, 256, 0, stream>>>(x, Wq, Wk, Wv, Wo, We,
                                             xbf, wqb, wkb, wvb, wob, wet);
    proj_mfma_kernel<<<dim3(4, 64, 3), 256, 0, stream>>>(xbf, wqb, wkb, wvb,
                                                         qw, kw, vtg,
                                                         0.125f * 1.44269504089f);
    attn_v10_kernel<<<1024, 256, 0, stream>>>(qw, kw, vtg, wet, awb);
    out_mfma_kernel<<<dim3(8, 128), 256, 0, stream>>>(awb, wob, bo, (float*)d_out);
}

// Round 6
// 173.416 us; speedup vs baseline: 1.0882x; 1.0882x over previous
//
#include <hip/hip_runtime.h>

#define Lc 1024
#define Dc 512
#define Hc 8
#define DHc 64

typedef __attribute__((ext_vector_type(8))) short bf16x8;
typedef __attribute__((ext_vector_type(4))) float f32x4;

typedef __attribute__((address_space(1))) const unsigned int guint;
typedef __attribute__((address_space(3))) unsigned int luint;

__device__ __forceinline__ void gload_lds16(const void* g, void* l) {
    __builtin_amdgcn_global_load_lds((guint*)g, (luint*)l, 16, 0, 0);
}

__device__ __forceinline__ unsigned short f2bf(float f) {
    unsigned u = __float_as_uint(f);
    u += 0x7fffu + ((u >> 16) & 1u);          // round-to-nearest-even
    return (unsigned short)(u >> 16);
}
__device__ __forceinline__ unsigned pk2(float a, float b) {
    return (unsigned)f2bf(a) | ((unsigned)f2bf(b) << 16);
}
__device__ __forceinline__ unsigned pk2t(float a, float b) {   // truncating pack, 1 v_perm
    return __builtin_amdgcn_perm(__float_as_uint(b), __float_as_uint(a), 0x07060302u);
}
__device__ __forceinline__ float bf2f(unsigned short s) { return __uint_as_float(((unsigned)s) << 16); }

// ---------------------------------------------------------------------------
// fp32 -> bf16 cast of x, Wq, Wk, Wv, Wo, We
// ---------------------------------------------------------------------------
__global__ void cvt_all_kernel(
    const float* __restrict__ x,  const float* __restrict__ Wq,
    const float* __restrict__ Wk, const float* __restrict__ Wv,
    const float* __restrict__ Wo, const float* __restrict__ We,
    unsigned short* __restrict__ xb,  unsigned short* __restrict__ wqb,
    unsigned short* __restrict__ wkb, unsigned short* __restrict__ wvb,
    unsigned short* __restrict__ wob, unsigned short* __restrict__ wet)
{
    int bid = blockIdx.x;
    const float* src; unsigned short* dst; size_t base;
    if      (bid < 4096) { src = x;  dst = xb;  base = (size_t)bid * 1024; }
    else if (bid < 4352) { src = Wq; dst = wqb; base = (size_t)(bid-4096) * 1024; }
    else if (bid < 4608) { src = Wk; dst = wkb; base = (size_t)(bid-4352) * 1024; }
    else if (bid < 4864) { src = Wv; dst = wvb; base = (size_t)(bid-4608) * 1024; }
    else if (bid < 5120) { src = Wo; dst = wob; base = (size_t)(bid-4864) * 1024; }
    else                 { src = We; dst = wet; base = (size_t)(bid-5120) * 1024; }
    size_t i = base + (size_t)threadIdx.x * 4;
    float4 a = *(const float4*)&src[i];
    *(uint2*)&dst[i] = make_uint2(pk2(a.x, a.y), pk2(a.z, a.w));
}

// ---------------------------------------------------------------------------
// QKV projection, bf16 MFMA, BK=64, full-DMA staging (R6-proven config).
// ---------------------------------------------------------------------------
__global__ __launch_bounds__(256, 3) void proj_mfma_kernel(
    const unsigned short* __restrict__ xb,
    const unsigned short* __restrict__ wq, const unsigned short* __restrict__ wk,
    const unsigned short* __restrict__ wv,
    unsigned short* __restrict__ qo, unsigned short* __restrict__ ko,
    unsigned short* __restrict__ vtg, float qscale)
{
    const unsigned short* W;
    if (blockIdx.z == 0)      W = wq;
    else if (blockIdx.z == 1) W = wk;
    else                      W = wv;

    __shared__ unsigned short smem[128 * 136];      // As(8192) Bs(8192) / Ts(17408)
    unsigned short* As = smem;
    unsigned short* Bs = smem + 8192;

    const int t = threadIdx.x;
    const int lane = t & 63, w = t >> 6;
    const int lq = lane >> 4, ln = lane & 15;
    const int m0 = blockIdx.y * 128, n0 = blockIdx.x * 128;
    const int wm = (w & 1) * 64, wn = (w >> 1) * 64;
    const int srow = t >> 3;                        // 0..31
    const int lsg  = ((t & 7) ^ ((t >> 3) & 7)) * 8;  // swizzled source seg*8
    const int key  = ln & 7;

    f32x4 acc[4][4];
    #pragma unroll
    for (int i = 0; i < 4; i++)
        #pragma unroll
        for (int j = 0; j < 4; j++) acc[i][j] = (f32x4){0.f,0.f,0.f,0.f};

    for (int c0 = 0; c0 < 512; c0 += 64) {
        __syncthreads();
        #pragma unroll
        for (int g = 0; g < 4; g++) {
            gload_lds16(&xb[(size_t)(m0 + 32*g + srow) * 512 + c0 + lsg], &As[(32*g + srow)*64 + (t&7)*8]);
            gload_lds16(&W [(size_t)(n0 + 32*g + srow) * 512 + c0 + lsg], &Bs[(32*g + srow)*64 + (t&7)*8]);
        }
        __syncthreads();

        #pragma unroll
        for (int kk = 0; kk < 2; kk++) {
            bf16x8 af[4], bf[4];
            #pragma unroll
            for (int i = 0; i < 4; i++)
                af[i] = *(bf16x8*)&As[(wm + 16*i + ln)*64 + ((kk*4 + lq) ^ key)*8];
            #pragma unroll
            for (int j = 0; j < 4; j++)
                bf[j] = *(bf16x8*)&Bs[(wn + 16*j + ln)*64 + ((kk*4 + lq) ^ key)*8];
            #pragma unroll
            for (int i = 0; i < 4; i++)
                #pragma unroll
                for (int j = 0; j < 4; j++)
                    acc[i][j] = __builtin_amdgcn_mfma_f32_16x16x32_bf16(af[i], bf[j], acc[i][j], 0, 0, 0);
        }
    }

    if (blockIdx.z < 2) {
        unsigned short* out = (blockIdx.z == 0) ? qo : ko;
        const float osc = (blockIdx.z == 0) ? qscale : 1.0f;
        #pragma unroll
        for (int i = 0; i < 4; i++) {
            #pragma unroll
            for (int r = 0; r < 4; r++) {
                int m = m0 + wm + 16*i + 4*lq + r;
                int b = m >> 10, l = m & 1023;
                #pragma unroll
                for (int j = 0; j < 4; j++) {
                    int n = n0 + wn + 16*j + ln;
                    int h = n >> 6, dh = n & 63;
                    out[((size_t)((b*Hc + h)*Lc + l))*DHc + dh] = f2bf(acc[i][j][r] * osc);
                }
            }
        }
    } else {
        // V: transpose through LDS, write V^T (B,H,DH,L)
        __syncthreads();
        unsigned short* Ts = smem;      // [n_local][m_local] stride 136
        #pragma unroll
        for (int i = 0; i < 4; i++) {
            int mlb = wm + 16*i + 4*lq;
            #pragma unroll
            for (int j = 0; j < 4; j++) {
                int nl = wn + 16*j + ln;
                *(uint2*)&Ts[nl*136 + mlb] = make_uint2(pk2(acc[i][j][0], acc[i][j][1]),
                                                        pk2(acc[i][j][2], acc[i][j][3]));
            }
        }
        __syncthreads();
        const int b = m0 >> 10, l0m = m0 & 1023;
        const int nl = t >> 1, seg = (t & 1) * 64;
        const int ng = n0 + nl, h = ng >> 6, dh = ng & 63;
        unsigned short* dst = vtg + (((size_t)(b*Hc + h))*DHc + dh)*Lc + l0m + seg;
        #pragma unroll
        for (int u = 0; u < 8; u++)
            *(uint4*)&dst[8*u] = *(uint4*)&Ts[nl*136 + seg + 8*u];
    }
}

// ---------------------------------------------------------------------------
// Output GEMM, bf16 MFMA, 64x64 tiles (1024 blocks = 4/CU). BK=64, swizzled
// DMA. out = awb @ Wo^T + bo (fp32 out).
// ---------------------------------------------------------------------------
__global__ __launch_bounds__(256, 4) void out_mfma_kernel(
    const unsigned short* __restrict__ A, const unsigned short* __restrict__ W,
    const float* __restrict__ bias, float* __restrict__ out)
{
    __shared__ unsigned short As[64 * 64];
    __shared__ unsigned short Bs[64 * 64];

    const int t = threadIdx.x;
    const int lane = t & 63, w = t >> 6;
    const int lq = lane >> 4, ln = lane & 15;
    const int m0 = blockIdx.y * 64, n0 = blockIdx.x * 64;
    const int wm = (w & 1) * 32, wn = (w >> 1) * 32;
    const int srow = t >> 3;                        // 0..31
    const int lsg  = ((t & 7) ^ ((t >> 3) & 7)) * 8;
    const int key  = ln & 7;

    f32x4 acc[2][2];
    #pragma unroll
    for (int i = 0; i < 2; i++)
        #pragma unroll
        for (int j = 0; j < 2; j++) acc[i][j] = (f32x4){0.f,0.f,0.f,0.f};

    for (int c0 = 0; c0 < 512; c0 += 64) {
        __syncthreads();
        #pragma unroll
        for (int g = 0; g < 2; g++) {
            gload_lds16(&A[(size_t)(m0 + 32*g + srow) * 512 + c0 + lsg], &As[(32*g + srow)*64 + (t&7)*8]);
            gload_lds16(&W[(size_t)(n0 + 32*g + srow) * 512 + c0 + lsg], &Bs[(32*g + srow)*64 + (t&7)*8]);
        }
        __syncthreads();

        #pragma unroll
        for (int kk = 0; kk < 2; kk++) {
            bf16x8 af[2], bf[2];
            #pragma unroll
            for (int i = 0; i < 2; i++)
                af[i] = *(bf16x8*)&As[(wm + 16*i + ln)*64 + ((kk*4 + lq) ^ key)*8];
            #pragma unroll
            for (int j = 0; j < 2; j++)
                bf[j] = *(bf16x8*)&Bs[(wn + 16*j + ln)*64 + ((kk*4 + lq) ^ key)*8];
            #pragma unroll
            for (int i = 0; i < 2; i++)
                #pragma unroll
                for (int j = 0; j < 2; j++)
                    acc[i][j] = __builtin_amdgcn_mfma_f32_16x16x32_bf16(af[i], bf[j], acc[i][j], 0, 0, 0);
        }
    }

    float bb[2];
    #pragma unroll
    for (int j = 0; j < 2; j++) bb[j] = bias[n0 + wn + 16*j + ln];

    #pragma unroll
    for (int i = 0; i < 2; i++) {
        #pragma unroll
        for (int r = 0; r < 4; r++) {
            int m = m0 + wm + 16*i + 4*lq + r;
            #pragma unroll
            for (int j = 0; j < 2; j++) {
                int n = n0 + wn + 16*j + ln;
                out[(size_t)m * Dc + n] = acc[i][j][r] + bb[j];
            }
        }
    }
}

// ---------------------------------------------------------------------------
// attn v11: v9 dataflow + staggered DMA schedule. Every __syncthreads drains
// vmcnt, so each DMA is issued at its earliest WAR-legal point and rides a
// full compute phase of slack to the next barrier:
//   vtp(i)    issued after B1 (freed by prev PV)   -> drained B2 (QE slack)
//   wesp(i+1) issued after B2 (freed by this QE)   -> drained B3 (bias slack)
//   ksp(i+1)  issued after B3 (freed by this QK)   -> drained next B1 (PV slack)
// This removes v9's dedicated zero-slack drain barrier: 4 -> 3 barriers/iter.
// wesp is now a dedicated single buffer staged one iter ahead (prologue
// stages panel pb0 into ps2 for the pre-loop QE). LDS 48 KB -> 3 blocks/CU
// (R1 evidence: 3 vs 4 blocks/CU is perf-neutral for this kernel).
// ---------------------------------------------------------------------------
__global__ __launch_bounds__(256, 4) void attn_v11_kernel(
    const unsigned short* __restrict__ q, const unsigned short* __restrict__ k,
    const unsigned short* __restrict__ vtg, const unsigned short* __restrict__ wet,
    unsigned short* __restrict__ attn)
{
    __shared__ unsigned short ksp [2 * 64 * 32];    // 8192  K planes [kk][s][32]
    __shared__ unsigned short vtp [2 * 64 * 32];    // 8192  V^T planes [kk][dh][32]
    __shared__ unsigned short wesp[2 * 64 * 32];    // 8192  We panel (1 iter ahead)
    __shared__ unsigned short ps2 [64 * 64];        // 8192  P^T exchange [l][s-swz]
    __shared__ unsigned short qes [128 * 64];       // 16384 QE ring [slot][col^swz]
    // total 49152 B -> 3 blocks/CU

    const int t    = threadIdx.x;
    const int lane = t & 63, w = t >> 6;
    const int lq   = lane >> 4, ln = lane & 15;
    const int si   = w >> 1;                        // s / dh half: 0/1
    const int li   = w & 1;                         // l half: 0/1

    const int n   = blockIdx.x;
    const int xcd = n & 7, idx = n >> 3;
    const int bh  = xcd * 8 + (idx >> 4);
    const int l0  = (idx & 15) * 64;

    const unsigned short* qb  = q   + (size_t)bh * (Lc * DHc);
    const unsigned short* kb  = k   + (size_t)bh * (Lc * DHc);
    const unsigned short* vtb = vtg + (size_t)bh * (DHc * Lc);

    const int trow = t >> 2;
    const int sseg = ((t & 3) ^ ((t >> 4) & 3)) * 8;
    const int swz  = (ln >> 2) & 3;

    const bf16x8 onesf = {(short)0x3F80,(short)0x3F80,(short)0x3F80,(short)0x3F80,
                          (short)0x3F80,(short)0x3F80,(short)0x3F80,(short)0x3F80};

    // Q fragments: lane ln <-> l = l0 + 32*li + 16*lt + ln; lq <-> dh chunk
    bf16x8 qf[2][2];
    #pragma unroll
    for (int lt = 0; lt < 2; lt++)
        #pragma unroll
        for (int kk = 0; kk < 2; kk++)
            qf[lt][kk] = *(const bf16x8*)&qb[(size_t)(l0 + 32*li + 16*lt + ln)*64 + kk*32 + lq*8];

    const int pb0 = 15 - (l0 >> 6);

    // prologue staging: panel pb0 -> ps2 (pre-loop QE only), panel pb0+1
    // (== newp of iter 0) -> wesp, K tile 0 -> ksp.
    gload_lds16(&wet[(size_t)(64*pb0 + trow)*64 +      sseg], &ps2 [t*8]);
    gload_lds16(&wet[(size_t)(64*pb0 + trow)*64 + 32 + sseg], &ps2 [2048 + t*8]);
    gload_lds16(&wet[(size_t)(64*(pb0+1) + trow)*64 +      sseg], &wesp[t*8]);
    gload_lds16(&wet[(size_t)(64*(pb0+1) + trow)*64 + 32 + sseg], &wesp[2048 + t*8]);
    gload_lds16(&kb [(size_t)trow*64 +      sseg], &ksp [t*8]);
    gload_lds16(&kb [(size_t)trow*64 + 32 + sseg], &ksp [2048 + t*8]);
    __syncthreads();

    // pre-loop QE panel pb0 (from ps2) -> ring
    {
        f32x4 qec[2][2];                            // [lt][et]
        #pragma unroll
        for (int lt = 0; lt < 2; lt++)
            #pragma unroll
            for (int et = 0; et < 2; et++) qec[lt][et] = (f32x4){0.f,0.f,0.f,0.f};
        #pragma unroll
        for (int kk = 0; kk < 2; kk++)
            #pragma unroll
            for (int et = 0; et < 2; et++) {
                bf16x8 wf = *(bf16x8*)&ps2[kk*2048 + (16*(2*si+et) + ln)*32 + (lq ^ swz)*8];
                #pragma unroll
                for (int lt = 0; lt < 2; lt++)
                    qec[lt][et] = __builtin_amdgcn_mfma_f32_16x16x32_bf16(qf[lt][kk], wf, qec[lt][et], 0, 0, 0);
            }
        const int cb = (pb0 & 1) * 64;
        #pragma unroll
        for (int et = 0; et < 2; et++) {
            const int row = cb + 16*(2*si+et) + ln;               // (row&15) == e&15
            #pragma unroll
            for (int lt = 0; lt < 2; lt++)
                *(uint2*)&qes[row*64 + ((32*li + 16*lt + 4*lq) ^ (ln << 2))] =
                    make_uint2(pk2(qec[lt][et][0], qec[lt][et][1]),
                               pk2(qec[lt][et][2], qec[lt][et][3]));
        }
    }

    f32x4 Lacc[2];
    f32x4 Ov[2][2];                                 // [dt][lt]
    #pragma unroll
    for (int lt = 0; lt < 2; lt++) {
        Lacc[lt] = (f32x4){0.f,0.f,0.f,0.f};
        #pragma unroll
        for (int dt = 0; dt < 2; dt++) Ov[dt][lt] = (f32x4){0.f,0.f,0.f,0.f};
    }

    int pbOld = pb0 - 1;

    #pragma unroll 1
    for (int s0 = 0; s0 < Lc; s0 += 64) {
        const int c0  = l0 - s0;
        const int ac0 = c0 < 0 ? -c0 : c0;
        const int pb  = (960 - ac0) >> 6;
        const int newp = (pb > pbOld) ? pb + 1 : pb;
        pbOld = pb;
        const int cb = (newp & 1) * 64;
        const bool more = (s0 < Lc - 64);
        // next-iter panel index (nnp == newp of iter i+1)
        const int nc  = c0 - 64;
        const int nac = nc < 0 ? -nc : nc;
        const int npb = (960 - nac) >> 6;
        const int nnp = (npb > pb) ? npb + 1 : npb;

        __syncthreads();                            // B1: prev PV done; ksp(i) drained

        // vtp(i): freed by prev PV; drains at B2 under the QE phase
        gload_lds16(&vtb[(size_t)trow*1024 + s0 +      sseg], &vtp[t*8]);
        gload_lds16(&vtb[(size_t)trow*1024 + s0 + 32 + sseg], &vtp[2048 + t*8]);

        // ---- QE: panel newp from wesp (staged last iter) -> ring ----
        {
            f32x4 qec[2][2];
            #pragma unroll
            for (int lt = 0; lt < 2; lt++)
                #pragma unroll
                for (int et = 0; et < 2; et++) qec[lt][et] = (f32x4){0.f,0.f,0.f,0.f};
            #pragma unroll
            for (int kk = 0; kk < 2; kk++)
                #pragma unroll
                for (int et = 0; et < 2; et++) {
                    bf16x8 wf = *(bf16x8*)&wesp[kk*2048 + (16*(2*si+et) + ln)*32 + (lq ^ swz)*8];
                    #pragma unroll
                    for (int lt = 0; lt < 2; lt++)
                        qec[lt][et] = __builtin_amdgcn_mfma_f32_16x16x32_bf16(qf[lt][kk], wf, qec[lt][et], 0, 0, 0);
                }
            #pragma unroll
            for (int et = 0; et < 2; et++) {
                const int row = cb + 16*(2*si+et) + ln;
                #pragma unroll
                for (int lt = 0; lt < 2; lt++)
                    *(uint2*)&qes[row*64 + ((32*li + 16*lt + 4*lq) ^ (ln << 2))] =
                        make_uint2(pk2(qec[lt][et][0], qec[lt][et][1]),
                                   pk2(qec[lt][et][2], qec[lt][et][3]));
            }
        }

        __syncthreads();                            // B2: ring visible; vtp drained; wesp free

        // wesp(i+1): freed by this QE; drains at B3 under the bias phase
        if (more) {
            gload_lds16(&wet[(size_t)(64*nnp + trow)*64 +      sseg], &wesp[t*8]);
            gload_lds16(&wet[(size_t)(64*nnp + trow)*64 + 32 + sseg], &wesp[2048 + t*8]);
        }

        // ---- S^T = mfma(K, Q): rows s = 32si+16st+4lq+r, cols l ----
        f32x4 sc[2][2];                             // [st][lt]
        #pragma unroll
        for (int st = 0; st < 2; st++)
            #pragma unroll
            for (int lt = 0; lt < 2; lt++) sc[st][lt] = (f32x4){0.f,0.f,0.f,0.f};
        #pragma unroll
        for (int kk = 0; kk < 2; kk++)
            #pragma unroll
            for (int st = 0; st < 2; st++) {
                bf16x8 kf = *(bf16x8*)&ksp[kk*2048 + (32*si + 16*st + ln)*32 + (lq ^ swz)*8];
                #pragma unroll
                for (int lt = 0; lt < 2; lt++)
                    sc[st][lt] = __builtin_amdgcn_mfma_f32_16x16x32_bf16(kf, qf[lt][kk], sc[st][lt], 0, 0, 0);
            }

        // ---- bias + exp2 + packed P^T write ----
        #pragma unroll
        for (int st = 0; st < 2; st++)
            #pragma unroll
            for (int lt = 0; lt < 2; lt++) {
                const int lloc = 32*li + 16*lt + ln;
                const int sb   = 32*si + 16*st + 4*lq;
                float p[4];
                #pragma unroll
                for (int r = 0; r < 4; r++) {
                    int d  = c0 + lloc - (sb + r);
                    int ad = d < 0 ? -d : d;
                    int m  = 1023 - ad;
                    float bias = bf2f(qes[(m & 127)*64 + (lloc ^ ((m & 15) << 2))]);
                    p[r] = __builtin_amdgcn_exp2f(sc[st][lt][r] + bias);
                }
                const int blk = (4*si + 2*st + (lq >> 1)) ^ (ln & 7);   // lloc&7 == ln&7
                *(uint2*)&ps2[lloc*64 + blk*8 + (lq & 1)*4] =
                    make_uint2(pk2t(p[0], p[1]), pk2t(p[2], p[3]));
            }

        __syncthreads();                            // B3: P visible; wesp(i+1) drained; ksp free

        // ksp(i+1): freed by this QK; drains at next B1 under the PV phase
        if (more) {
            gload_lds16(&kb[(size_t)(s0 + 64 + trow)*64 +      sseg], &ksp[t*8]);
            gload_lds16(&kb[(size_t)(s0 + 64 + trow)*64 + 32 + sseg], &ksp[2048 + t*8]);
        }

        // ---- O^T = mfma(V^T, P^T): rows dh = 32si+16dt+4lq+r, cols l ----
        #pragma unroll
        for (int kk = 0; kk < 2; kk++) {
            bf16x8 pf[2];
            #pragma unroll
            for (int lt = 0; lt < 2; lt++) {
                const int row = 32*li + 16*lt + ln;
                pf[lt] = *(bf16x8*)&ps2[row*64 + ((4*kk + lq) ^ (ln & 7))*8];
            }
            #pragma unroll
            for (int lt = 0; lt < 2; lt++)
                Lacc[lt] = __builtin_amdgcn_mfma_f32_16x16x32_bf16(onesf, pf[lt], Lacc[lt], 0, 0, 0);
            #pragma unroll
            for (int dt = 0; dt < 2; dt++) {
                bf16x8 vf = *(bf16x8*)&vtp[kk*2048 + (32*si + 16*dt + ln)*32 + (lq ^ swz)*8];
                #pragma unroll
                for (int lt = 0; lt < 2; lt++)
                    Ov[dt][lt] = __builtin_amdgcn_mfma_f32_16x16x32_bf16(vf, pf[lt], Ov[dt][lt], 0, 0, 0);
            }
        }
    }

    const int b = bh >> 3, h = bh & 7;
    #pragma unroll
    for (int lt = 0; lt < 2; lt++) {
        const float inv = 1.f / Lacc[lt][0];        // all 4 rows identical
        const int l = l0 + 32*li + 16*lt + ln;
        unsigned short* dst = &attn[((size_t)(b*Lc + l))*Dc + h*DHc];
        #pragma unroll
        for (int dt = 0; dt < 2; dt++) {
            const int dh = 32*si + 16*dt + 4*lq;
            *(uint2*)&dst[dh] = make_uint2(pk2(Ov[dt][lt][0]*inv, Ov[dt][lt][1]*inv),
                                           pk2(Ov[dt][lt][2]*inv, Ov[dt][lt][3]*inv));
        }
    }
}

extern "C" void kernel_launch(void* const* d_in, const int* in_sizes, int n_in,
                              void* d_out, int out_size, void* d_ws, size_t ws_size,
                              hipStream_t stream)
{
    (void)in_sizes; (void)n_in; (void)out_size; (void)ws_size;
    const float* x  = (const float*)d_in[0];
    const float* Wq = (const float*)d_in[1];
    const float* Wk = (const float*)d_in[2];
    const float* Wv = (const float*)d_in[3];
    const float* We = (const float*)d_in[4];
    const float* Wo = (const float*)d_in[5];
    const float* bo = (const float*)d_in[6];

    const size_t NT = (size_t)8 * Hc * Lc * DHc;     // 4,194,304 elems
    unsigned short* qw  = (unsigned short*)d_ws;
    unsigned short* kw  = qw  + NT;
    unsigned short* vtg = kw  + NT;                  // V^T (B,H,DH,L)
    unsigned short* xbf = vtg + NT;
    unsigned short* awb = xbf + NT;                  // attn out bf16 (B,L,D)
    unsigned short* wqb = awb + NT;
    unsigned short* wkb = wqb + 262144;
    unsigned short* wvb = wkb + 262144;
    unsigned short* wob = wvb + 262144;
    unsigned short* wet = wob + 262144;              // 65536 + 4096 pad (panel-16 DMA overread)

    cvt_all_kernel<<<5184, 256, 0, stream>>>(x, Wq, Wk, Wv, Wo, We,
                                             xbf, wqb, wkb, wvb, wob, wet);
    proj_mfma_kernel<<<dim3(4, 64, 3), 256, 0, stream>>>(xbf, wqb, wkb, wvb,
                                                         qw, kw, vtg,
                                                         0.125f * 1.44269504089f);
    attn_v11_kernel<<<1024, 256, 0, stream>>>(qw, kw, vtg, wet, awb);
    out_mfma_kernel<<<dim3(8, 128), 256, 0, stream>>>(awb, wob, bo, (float*)d_out);
}

// Round 7
// 167.170 us; speedup vs baseline: 1.1289x; 1.0374x over previous
//
#include <hip/hip_runtime.h>

#define Lc 1024
#define Dc 512
#define Hc 8
#define DHc 64

typedef __attribute__((ext_vector_type(8))) short bf16x8;
typedef __attribute__((ext_vector_type(4))) float f32x4;
typedef __attribute__((ext_vector_type(16))) float f32x16;

typedef __attribute__((address_space(1))) const unsigned int guint;
typedef __attribute__((address_space(3))) unsigned int luint;

__device__ __forceinline__ void gload_lds16(const void* g, void* l) {
    __builtin_amdgcn_global_load_lds((guint*)g, (luint*)l, 16, 0, 0);
}

__device__ __forceinline__ unsigned short f2bf(float f) {
    unsigned u = __float_as_uint(f);
    u += 0x7fffu + ((u >> 16) & 1u);          // round-to-nearest-even
    return (unsigned short)(u >> 16);
}
__device__ __forceinline__ unsigned pk2(float a, float b) {
    return (unsigned)f2bf(a) | ((unsigned)f2bf(b) << 16);
}
__device__ __forceinline__ unsigned pk2t(float a, float b) {   // truncating pack, 1 v_perm
    return __builtin_amdgcn_perm(__float_as_uint(b), __float_as_uint(a), 0x07060302u);
}
__device__ __forceinline__ float bf2f(unsigned short s) { return __uint_as_float(((unsigned)s) << 16); }

// v_permlane32_swap_b32: a' = {a.lo, b.lo}; b' = {a.hi, b.hi}
// (lane<32: a'=own a, b'=partner(+32)'s a; lane>=32: a'=partner(-32)'s b, b'=own b)
__device__ __forceinline__ void pl32swap(unsigned &a, unsigned &b) {
    asm volatile("v_permlane32_swap_b32 %0, %1" : "+v"(a), "+v"(b));
}

// ---------------------------------------------------------------------------
// fp32 -> bf16 cast of x, Wq, Wk, Wv, Wo, We
// ---------------------------------------------------------------------------
__global__ void cvt_all_kernel(
    const float* __restrict__ x,  const float* __restrict__ Wq,
    const float* __restrict__ Wk, const float* __restrict__ Wv,
    const float* __restrict__ Wo, const float* __restrict__ We,
    unsigned short* __restrict__ xb,  unsigned short* __restrict__ wqb,
    unsigned short* __restrict__ wkb, unsigned short* __restrict__ wvb,
    unsigned short* __restrict__ wob, unsigned short* __restrict__ wet)
{
    int bid = blockIdx.x;
    const float* src; unsigned short* dst; size_t base;
    if      (bid < 4096) { src = x;  dst = xb;  base = (size_t)bid * 1024; }
    else if (bid < 4352) { src = Wq; dst = wqb; base = (size_t)(bid-4096) * 1024; }
    else if (bid < 4608) { src = Wk; dst = wkb; base = (size_t)(bid-4352) * 1024; }
    else if (bid < 4864) { src = Wv; dst = wvb; base = (size_t)(bid-4608) * 1024; }
    else if (bid < 5120) { src = Wo; dst = wob; base = (size_t)(bid-4864) * 1024; }
    else                 { src = We; dst = wet; base = (size_t)(bid-5120) * 1024; }
    size_t i = base + (size_t)threadIdx.x * 4;
    float4 a = *(const float4*)&src[i];
    *(uint2*)&dst[i] = make_uint2(pk2(a.x, a.y), pk2(a.z, a.w));
}

// ---------------------------------------------------------------------------
// QKV projection, bf16 MFMA, BK=64, full-DMA staging (R6-proven config).
// ---------------------------------------------------------------------------
__global__ __launch_bounds__(256, 3) void proj_mfma_kernel(
    const unsigned short* __restrict__ xb,
    const unsigned short* __restrict__ wq, const unsigned short* __restrict__ wk,
    const unsigned short* __restrict__ wv,
    unsigned short* __restrict__ qo, unsigned short* __restrict__ ko,
    unsigned short* __restrict__ vtg, float qscale)
{
    const unsigned short* W;
    if (blockIdx.z == 0)      W = wq;
    else if (blockIdx.z == 1) W = wk;
    else                      W = wv;

    __shared__ unsigned short smem[128 * 136];      // As(8192) Bs(8192) / Ts(17408)
    unsigned short* As = smem;
    unsigned short* Bs = smem + 8192;

    const int t = threadIdx.x;
    const int lane = t & 63, w = t >> 6;
    const int lq = lane >> 4, ln = lane & 15;
    const int m0 = blockIdx.y * 128, n0 = blockIdx.x * 128;
    const int wm = (w & 1) * 64, wn = (w >> 1) * 64;
    const int srow = t >> 3;                        // 0..31
    const int lsg  = ((t & 7) ^ ((t >> 3) & 7)) * 8;  // swizzled source seg*8
    const int key  = ln & 7;

    f32x4 acc[4][4];
    #pragma unroll
    for (int i = 0; i < 4; i++)
        #pragma unroll
        for (int j = 0; j < 4; j++) acc[i][j] = (f32x4){0.f,0.f,0.f,0.f};

    for (int c0 = 0; c0 < 512; c0 += 64) {
        __syncthreads();
        #pragma unroll
        for (int g = 0; g < 4; g++) {
            gload_lds16(&xb[(size_t)(m0 + 32*g + srow) * 512 + c0 + lsg], &As[(32*g + srow)*64 + (t&7)*8]);
            gload_lds16(&W [(size_t)(n0 + 32*g + srow) * 512 + c0 + lsg], &Bs[(32*g + srow)*64 + (t&7)*8]);
        }
        __syncthreads();

        #pragma unroll
        for (int kk = 0; kk < 2; kk++) {
            bf16x8 af[4], bf[4];
            #pragma unroll
            for (int i = 0; i < 4; i++)
                af[i] = *(bf16x8*)&As[(wm + 16*i + ln)*64 + ((kk*4 + lq) ^ key)*8];
            #pragma unroll
            for (int j = 0; j < 4; j++)
                bf[j] = *(bf16x8*)&Bs[(wn + 16*j + ln)*64 + ((kk*4 + lq) ^ key)*8];
            #pragma unroll
            for (int i = 0; i < 4; i++)
                #pragma unroll
                for (int j = 0; j < 4; j++)
                    acc[i][j] = __builtin_amdgcn_mfma_f32_16x16x32_bf16(af[i], bf[j], acc[i][j], 0, 0, 0);
        }
    }

    if (blockIdx.z < 2) {
        unsigned short* out = (blockIdx.z == 0) ? qo : ko;
        const float osc = (blockIdx.z == 0) ? qscale : 1.0f;
        #pragma unroll
        for (int i = 0; i < 4; i++) {
            #pragma unroll
            for (int r = 0; r < 4; r++) {
                int m = m0 + wm + 16*i + 4*lq + r;
                int b = m >> 10, l = m & 1023;
                #pragma unroll
                for (int j = 0; j < 4; j++) {
                    int n = n0 + wn + 16*j + ln;
                    int h = n >> 6, dh = n & 63;
                    out[((size_t)((b*Hc + h)*Lc + l))*DHc + dh] = f2bf(acc[i][j][r] * osc);
                }
            }
        }
    } else {
        // V: transpose through LDS, write V^T (B,H,DH,L)
        __syncthreads();
        unsigned short* Ts = smem;      // [n_local][m_local] stride 136
        #pragma unroll
        for (int i = 0; i < 4; i++) {
            int mlb = wm + 16*i + 4*lq;
            #pragma unroll
            for (int j = 0; j < 4; j++) {
                int nl = wn + 16*j + ln;
                *(uint2*)&Ts[nl*136 + mlb] = make_uint2(pk2(acc[i][j][0], acc[i][j][1]),
                                                        pk2(acc[i][j][2], acc[i][j][3]));
            }
        }
        __syncthreads();
        const int b = m0 >> 10, l0m = m0 & 1023;
        const int nl = t >> 1, seg = (t & 1) * 64;
        const int ng = n0 + nl, h = ng >> 6, dh = ng & 63;
        unsigned short* dst = vtg + (((size_t)(b*Hc + h))*DHc + dh)*Lc + l0m + seg;
        #pragma unroll
        for (int u = 0; u < 8; u++)
            *(uint4*)&dst[8*u] = *(uint4*)&Ts[nl*136 + seg + 8*u];
    }
}

// ---------------------------------------------------------------------------
// Output GEMM, bf16 MFMA, 64x64 tiles (1024 blocks = 4/CU). BK=64, swizzled
// DMA. out = awb @ Wo^T + bo (fp32 out).
// ---------------------------------------------------------------------------
__global__ __launch_bounds__(256, 4) void out_mfma_kernel(
    const unsigned short* __restrict__ A, const unsigned short* __restrict__ W,
    const float* __restrict__ bias, float* __restrict__ out)
{
    __shared__ unsigned short As[64 * 64];
    __shared__ unsigned short Bs[64 * 64];

    const int t = threadIdx.x;
    const int lane = t & 63, w = t >> 6;
    const int lq = lane >> 4, ln = lane & 15;
    const int m0 = blockIdx.y * 64, n0 = blockIdx.x * 64;
    const int wm = (w & 1) * 32, wn = (w >> 1) * 32;
    const int srow = t >> 3;                        // 0..31
    const int lsg  = ((t & 7) ^ ((t >> 3) & 7)) * 8;
    const int key  = ln & 7;

    f32x4 acc[2][2];
    #pragma unroll
    for (int i = 0; i < 2; i++)
        #pragma unroll
        for (int j = 0; j < 2; j++) acc[i][j] = (f32x4){0.f,0.f,0.f,0.f};

    for (int c0 = 0; c0 < 512; c0 += 64) {
        __syncthreads();
        #pragma unroll
        for (int g = 0; g < 2; g++) {
            gload_lds16(&A[(size_t)(m0 + 32*g + srow) * 512 + c0 + lsg], &As[(32*g + srow)*64 + (t&7)*8]);
            gload_lds16(&W[(size_t)(n0 + 32*g + srow) * 512 + c0 + lsg], &Bs[(32*g + srow)*64 + (t&7)*8]);
        }
        __syncthreads();

        #pragma unroll
        for (int kk = 0; kk < 2; kk++) {
            bf16x8 af[2], bf[2];
            #pragma unroll
            for (int i = 0; i < 2; i++)
                af[i] = *(bf16x8*)&As[(wm + 16*i + ln)*64 + ((kk*4 + lq) ^ key)*8];
            #pragma unroll
            for (int j = 0; j < 2; j++)
                bf[j] = *(bf16x8*)&Bs[(wn + 16*j + ln)*64 + ((kk*4 + lq) ^ key)*8];
            #pragma unroll
            for (int i = 0; i < 2; i++)
                #pragma unroll
                for (int j = 0; j < 2; j++)
                    acc[i][j] = __builtin_amdgcn_mfma_f32_16x16x32_bf16(af[i], bf[j], acc[i][j], 0, 0, 0);
        }
    }

    float bb[2];
    #pragma unroll
    for (int j = 0; j < 2; j++) bb[j] = bias[n0 + wn + 16*j + ln];

    #pragma unroll
    for (int i = 0; i < 2; i++) {
        #pragma unroll
        for (int r = 0; r < 4; r++) {
            int m = m0 + wm + 16*i + 4*lq + r;
            #pragma unroll
            for (int j = 0; j < 2; j++) {
                int n = n0 + wn + 16*j + ln;
                out[(size_t)m * Dc + n] = acc[i][j][r] + bb[j];
            }
        }
    }
}

// ---------------------------------------------------------------------------
// attn v12: 32x32x16 MFMAs everywhere; P exchange fully in registers via
// v_permlane32_swap_b32 (the 16x16 lq-mismatch becomes a pure lane^32 swap).
// - ps2 eliminated: -4 uint2 writes, -4 b128 reads per wave-iter, -8KB LDS
// - each wave PV-contracts its own s-half; one cross-si epilogue reduce (LDS)
// - K/V/We staged as [64 rows][128B] with (t&7)^((t>>3)&7) chunk swizzle
// - ring/panel logic, bias formula, 3-barrier skeleton: unchanged from v11
// LDS 40960 B -> 4 blocks/CU.
// ---------------------------------------------------------------------------
__global__ __launch_bounds__(256, 4) void attn_v12_kernel(
    const unsigned short* __restrict__ q, const unsigned short* __restrict__ k,
    const unsigned short* __restrict__ vtg, const unsigned short* __restrict__ wet,
    unsigned short* __restrict__ attn)
{
    __shared__ unsigned short smem[20480];          // 40960 B total
    unsigned short* ksp  = smem;                    // 8192 B  K     [s][dh swz]
    unsigned short* vtp  = smem + 4096;             // 8192 B  V^T   [dh][s swz]  (prologue: We pb0)
    unsigned short* wesp = smem + 8192;             // 8192 B  We    [e][dh swz]  (1 iter ahead)
    unsigned short* qes  = smem + 12288;            // 16384 B QE ring [slot][l^swz]

    const int t    = threadIdx.x;
    const int lane = t & 63, w = t >> 6;
    const int ln31 = lane & 31, hi = lane >> 5;
    const int si   = w >> 1;                        // s / e half: 0/1
    const int li   = w & 1;                         // l half: 0/1

    const int n   = blockIdx.x;
    const int xcd = n & 7, idx = n >> 3;
    const int bh  = xcd * 8 + (idx >> 4);
    const int l0  = (idx & 15) * 64;

    const unsigned short* qb  = q   + (size_t)bh * (Lc * DHc);
    const unsigned short* kb  = k   + (size_t)bh * (Lc * DHc);
    const unsigned short* vtb = vtg + (size_t)bh * (DHc * Lc);

    const int srow2 = t >> 3;                       // 0..31 staging row
    const int lsg2  = ((t & 7) ^ ((t >> 3) & 7)) * 8;
    const int k7    = ln31 & 7;
    const int lloc  = 32*li + ln31;

    // Q fragments (serve both A and B operand slots): Q[l][dh=16kk+8hi+j]
    bf16x8 qf[4];
    #pragma unroll
    for (int kk = 0; kk < 4; kk++)
        qf[kk] = *(const bf16x8*)&qb[(size_t)(l0 + lloc)*64 + kk*16 + hi*8];

    const int pb0 = 15 - (l0 >> 6);

    // prologue staging: panel pb0 -> vtp (scratch, pre-loop QE only),
    // panel pb0+1 (= newp of iter 0) -> wesp, K tile 0 -> ksp
    gload_lds16(&wet[(size_t)(64*pb0 + srow2)*64 + lsg2],        &vtp [t*8]);
    gload_lds16(&wet[(size_t)(64*pb0 + 32 + srow2)*64 + lsg2],   &vtp [2048 + t*8]);
    gload_lds16(&wet[(size_t)(64*(pb0+1) + srow2)*64 + lsg2],    &wesp[t*8]);
    gload_lds16(&wet[(size_t)(64*(pb0+1) + 32 + srow2)*64 + lsg2], &wesp[2048 + t*8]);
    gload_lds16(&kb [(size_t)srow2*64 + lsg2],                   &ksp [t*8]);
    gload_lds16(&kb [(size_t)(32 + srow2)*64 + lsg2],            &ksp [2048 + t*8]);
    __syncthreads();

    // pre-loop QE panel pb0 (from vtp scratch) -> ring
    {
        f32x16 qec = (f32x16){0.f,0.f,0.f,0.f,0.f,0.f,0.f,0.f,0.f,0.f,0.f,0.f,0.f,0.f,0.f,0.f};
        #pragma unroll
        for (int kk = 0; kk < 4; kk++) {
            bf16x8 wf = *(bf16x8*)&vtp[(32*si + ln31)*64 + ((2*kk + hi) ^ k7)*8];
            qec = __builtin_amdgcn_mfma_f32_32x32x16_bf16(qf[kk], wf, qec, 0, 0, 0);
        }
        const int rs = ((pb0 & 1)*64 + 32*si + ln31) * 64;
        #pragma unroll
        for (int g = 0; g < 4; g++) {
            const int col = (32*li + 8*g + 4*hi) ^ ((ln31 & 15) << 2);
            *(uint2*)&qes[rs + col] = make_uint2(pk2(qec[4*g], qec[4*g+1]),
                                                 pk2(qec[4*g+2], qec[4*g+3]));
        }
    }

    f32x16 Ov[2];
    #pragma unroll
    for (int dt = 0; dt < 2; dt++)
        Ov[dt] = (f32x16){0.f,0.f,0.f,0.f,0.f,0.f,0.f,0.f,0.f,0.f,0.f,0.f,0.f,0.f,0.f,0.f};
    float Lacc = 0.f;

    int pbOld = pb0 - 1;

    #pragma unroll 1
    for (int s0 = 0; s0 < Lc; s0 += 64) {
        const int c0  = l0 - s0;
        const int ac0 = c0 < 0 ? -c0 : c0;
        const int pb  = (960 - ac0) >> 6;
        const int newp = (pb > pbOld) ? pb + 1 : pb;
        pbOld = pb;
        const int cb = (newp & 1) * 64;
        const bool more = (s0 < Lc - 64);
        const int nc  = c0 - 64;
        const int nac = nc < 0 ? -nc : nc;
        const int npb = (960 - nac) >> 6;
        const int nnp = (npb > pb) ? npb + 1 : npb;   // newp of iter i+1

        __syncthreads();                            // B1: prev PV done (vtp free); ring writable; ksp(i) drained

        // vtp(i): drains at B2 under the QE phase; consumed at PV
        gload_lds16(&vtb[(size_t)srow2*1024 + s0 + lsg2],        &vtp[t*8]);
        gload_lds16(&vtb[(size_t)(32 + srow2)*1024 + s0 + lsg2], &vtp[2048 + t*8]);

        // ---- QE: panel newp from wesp (staged last iter) -> ring ----
        {
            f32x16 qec = (f32x16){0.f,0.f,0.f,0.f,0.f,0.f,0.f,0.f,0.f,0.f,0.f,0.f,0.f,0.f,0.f,0.f};
            #pragma unroll
            for (int kk = 0; kk < 4; kk++) {
                bf16x8 wf = *(bf16x8*)&wesp[(32*si + ln31)*64 + ((2*kk + hi) ^ k7)*8];
                qec = __builtin_amdgcn_mfma_f32_32x32x16_bf16(qf[kk], wf, qec, 0, 0, 0);
            }
            const int rs = (cb + 32*si + ln31) * 64;
            #pragma unroll
            for (int g = 0; g < 4; g++) {
                const int col = (32*li + 8*g + 4*hi) ^ ((ln31 & 15) << 2);
                *(uint2*)&qes[rs + col] = make_uint2(pk2(qec[4*g], qec[4*g+1]),
                                                     pk2(qec[4*g+2], qec[4*g+3]));
            }
        }

        __syncthreads();                            // B2: ring visible; vtp drained; wesp free

        // wesp(i+1): drains at B3 under the QK+bias phase
        if (more) {
            gload_lds16(&wet[(size_t)(64*nnp + srow2)*64 + lsg2],      &wesp[t*8]);
            gload_lds16(&wet[(size_t)(64*nnp + 32 + srow2)*64 + lsg2], &wesp[2048 + t*8]);
        }

        // ---- S^T = mfma(K, Q): rows s = (reg&3)+8(reg>>2)+4hi + 32si, col l = lloc
        f32x16 sc = (f32x16){0.f,0.f,0.f,0.f,0.f,0.f,0.f,0.f,0.f,0.f,0.f,0.f,0.f,0.f,0.f,0.f};
        #pragma unroll
        for (int kk = 0; kk < 4; kk++) {
            bf16x8 kf = *(bf16x8*)&ksp[(32*si + ln31)*64 + ((2*kk + hi) ^ k7)*8];
            sc = __builtin_amdgcn_mfma_f32_32x32x16_bf16(kf, qf[kk], sc, 0, 0, 0);
        }

        // ---- bias + exp2; pack P; in-register exchange -> PV B-frags ----
        float p[16];
        #pragma unroll
        for (int g = 0; g < 4; g++) {
            const int sb = 32*si + 8*g + 4*hi;
            #pragma unroll
            for (int r = 0; r < 4; r++) {
                int d  = c0 + lloc - sb - r;
                int ad = d < 0 ? -d : d;
                int m  = 1023 - ad;
                float bias = bf2f(qes[(m & 127)*64 + (lloc ^ ((m & 15) << 2))]);
                p[4*g + r] = __builtin_amdgcn_exp2f(sc[4*g + r] + bias);
            }
        }
        // Lacc partial (this lane's 16 s-rows for its l)
        {
            float t0 = (p[0]+p[1]) + (p[2]+p[3]);
            float t1 = (p[4]+p[5]) + (p[6]+p[7]);
            float t2 = (p[8]+p[9]) + (p[10]+p[11]);
            float t3 = (p[12]+p[13]) + (p[14]+p[15]);
            Lacc += (t0 + t1) + (t2 + t3);
        }
        unsigned d0[4], d1[4];
        #pragma unroll
        for (int g = 0; g < 4; g++) {
            d0[g] = pk2t(p[4*g],     p[4*g + 1]);
            d1[g] = pk2t(p[4*g + 2], p[4*g + 3]);
        }
        bf16x8 pfr[2];
        #pragma unroll
        for (int kk = 0; kk < 2; kk++) {
            pl32swap(d0[2*kk], d0[2*kk + 1]);
            pl32swap(d1[2*kk], d1[2*kk + 1]);
            uint4 fu = make_uint4(d0[2*kk], d1[2*kk], d0[2*kk + 1], d1[2*kk + 1]);
            pfr[kk] = *(bf16x8*)&fu;
        }

        __syncthreads();                            // B3: ksp free (QK done); ring reads done; wesp(i+1) drained

        // ksp(i+1): drains at next B1 under the PV phase
        if (more) {
            gload_lds16(&kb[(size_t)(s0 + 64 + srow2)*64 + lsg2],      &ksp[t*8]);
            gload_lds16(&kb[(size_t)(s0 + 64 + 32 + srow2)*64 + lsg2], &ksp[2048 + t*8]);
        }

        // ---- O^T += mfma(V^T, P^T) over this wave's s-half ----
        #pragma unroll
        for (int kk = 0; kk < 2; kk++)
            #pragma unroll
            for (int dt = 0; dt < 2; dt++) {
                bf16x8 vf = *(bf16x8*)&vtp[(32*dt + ln31)*64 + (((4*si + 2*kk + hi) ^ k7))*8];
                Ov[dt] = __builtin_amdgcn_mfma_f32_32x32x16_bf16(vf, pfr[kk], Ov[dt], 0, 0, 0);
            }
    }

    // ---- epilogue: hi-merge Lacc, cross-si reduce via LDS, normalize, store
    unsigned la = __float_as_uint(Lacc), lb = la;
    pl32swap(la, lb);
    float Lh = Lacc + __uint_as_float(hi ? la : lb);   // full si-half denominator

    __syncthreads();
    float* scr = (float*)smem;                       // 33*128 f32 = 16.9 KB
    if (si == 1) {
        #pragma unroll
        for (int dt = 0; dt < 2; dt++)
            #pragma unroll
            for (int rg = 0; rg < 16; rg++)
                scr[(dt*16 + rg)*128 + li*64 + lane] = Ov[dt][rg];
        scr[32*128 + li*64 + lane] = Lh;
    }
    __syncthreads();
    if (si == 0) {
        const float Lt = Lh + scr[32*128 + li*64 + lane];
        const float inv = 1.f / Lt;
        const int b = bh >> 3, h = bh & 7;
        const int lg = l0 + lloc;
        unsigned short* dst = attn + ((size_t)(b*Lc + lg))*Dc + h*DHc;
        #pragma unroll
        for (int dt = 0; dt < 2; dt++)
            #pragma unroll
            for (int g = 0; g < 4; g++) {
                float v0 = (Ov[dt][4*g]   + scr[(dt*16 + 4*g)*128 + li*64 + lane]) * inv;
                float v1 = (Ov[dt][4*g+1] + scr[(dt*16 + 4*g+1)*128 + li*64 + lane]) * inv;
                float v2 = (Ov[dt][4*g+2] + scr[(dt*16 + 4*g+2)*128 + li*64 + lane]) * inv;
                float v3 = (Ov[dt][4*g+3] + scr[(dt*16 + 4*g+3)*128 + li*64 + lane]) * inv;
                *(uint2*)&dst[32*dt + 8*g + 4*hi] = make_uint2(pk2(v0, v1), pk2(v2, v3));
            }
    }
}

extern "C" void kernel_launch(void* const* d_in, const int* in_sizes, int n_in,
                              void* d_out, int out_size, void* d_ws, size_t ws_size,
                              hipStream_t stream)
{
    (void)in_sizes; (void)n_in; (void)out_size; (void)ws_size;
    const float* x  = (const float*)d_in[0];
    const float* Wq = (const float*)d_in[1];
    const float* Wk = (const float*)d_in[2];
    const float* Wv = (const float*)d_in[3];
    const float* We = (const float*)d_in[4];
    const float* Wo = (const float*)d_in[5];
    const float* bo = (const float*)d_in[6];

    const size_t NT = (size_t)8 * Hc * Lc * DHc;     // 4,194,304 elems
    unsigned short* qw  = (unsigned short*)d_ws;
    unsigned short* kw  = qw  + NT;
    unsigned short* vtg = kw  + NT;                  // V^T (B,H,DH,L)
    unsigned short* xbf = vtg + NT;
    unsigned short* awb = xbf + NT;                  // attn out bf16 (B,L,D)
    unsigned short* wqb = awb + NT;
    unsigned short* wkb = wqb + 262144;
    unsigned short* wvb = wkb + 262144;
    unsigned short* wob = wvb + 262144;
    unsigned short* wet = wob + 262144;              // 65536 + 4096 pad (panel-16 DMA overread)

    cvt_all_kernel<<<5184, 256, 0, stream>>>(x, Wq, Wk, Wv, Wo, We,
                                             xbf, wqb, wkb, wvb, wob, wet);
    proj_mfma_kernel<<<dim3(4, 64, 3), 256, 0, stream>>>(xbf, wqb, wkb, wvb,
                                                         qw, kw, vtg,
                                                         0.125f * 1.44269504089f);
    attn_v12_kernel<<<1024, 256, 0, stream>>>(qw, kw, vtg, wet, awb);
    out_mfma_kernel<<<dim3(8, 128), 256, 0, stream>>>(awb, wob, bo, (float*)d_out);
}

// Round 8
// 167.115 us; speedup vs baseline: 1.1293x; 1.0003x over previous
//
#include <hip/hip_runtime.h>

#define Lc 1024
#define Dc 512
#define Hc 8
#define DHc 64

typedef __attribute__((ext_vector_type(8))) short bf16x8;
typedef __attribute__((ext_vector_type(4))) float f32x4;
typedef __attribute__((ext_vector_type(16))) float f32x16;

typedef __attribute__((address_space(1))) const unsigned int guint;
typedef __attribute__((address_space(3))) unsigned int luint;

__device__ __forceinline__ void gload_lds16(const void* g, void* l) {
    __builtin_amdgcn_global_load_lds((guint*)g, (luint*)l, 16, 0, 0);
}

__device__ __forceinline__ unsigned short f2bf(float f) {
    unsigned u = __float_as_uint(f);
    u += 0x7fffu + ((u >> 16) & 1u);          // round-to-nearest-even
    return (unsigned short)(u >> 16);
}
__device__ __forceinline__ unsigned pk2(float a, float b) {
    return (unsigned)f2bf(a) | ((unsigned)f2bf(b) << 16);
}
__device__ __forceinline__ unsigned pk2t(float a, float b) {   // truncating pack, 1 v_perm
    return __builtin_amdgcn_perm(__float_as_uint(b), __float_as_uint(a), 0x07060302u);
}
__device__ __forceinline__ float bf2f(unsigned short s) { return __uint_as_float(((unsigned)s) << 16); }

// v_permlane32_swap_b32: a' = {a.lo, b.lo}; b' = {a.hi, b.hi}
__device__ __forceinline__ void pl32swap(unsigned &a, unsigned &b) {
    asm volatile("v_permlane32_swap_b32 %0, %1" : "+v"(a), "+v"(b));
}

// ---------------------------------------------------------------------------
// fp32 -> bf16 cast of x, Wq, Wk, Wv, Wo, We.
// v13: 2592 blocks x 2048 elems (2 float4 loads / thread, one uint4 store).
// ---------------------------------------------------------------------------
__global__ void cvt_all_kernel(
    const float* __restrict__ x,  const float* __restrict__ Wq,
    const float* __restrict__ Wk, const float* __restrict__ Wv,
    const float* __restrict__ Wo, const float* __restrict__ We,
    unsigned short* __restrict__ xb,  unsigned short* __restrict__ wqb,
    unsigned short* __restrict__ wkb, unsigned short* __restrict__ wvb,
    unsigned short* __restrict__ wob, unsigned short* __restrict__ wet)
{
    int bid = blockIdx.x;
    const float* src; unsigned short* dst; size_t base;
    if      (bid < 2048) { src = x;  dst = xb;  base = (size_t)bid * 2048; }
    else if (bid < 2176) { src = Wq; dst = wqb; base = (size_t)(bid-2048) * 2048; }
    else if (bid < 2304) { src = Wk; dst = wkb; base = (size_t)(bid-2176) * 2048; }
    else if (bid < 2432) { src = Wv; dst = wvb; base = (size_t)(bid-2304) * 2048; }
    else if (bid < 2560) { src = Wo; dst = wob; base = (size_t)(bid-2432) * 2048; }
    else                 { src = We; dst = wet; base = (size_t)(bid-2560) * 2048; }
    size_t i = base + (size_t)threadIdx.x * 8;
    float4 a = *(const float4*)&src[i];
    float4 b = *(const float4*)&src[i + 4];
    uint4 o = make_uint4(pk2(a.x, a.y), pk2(a.z, a.w), pk2(b.x, b.y), pk2(b.z, b.w));
    *(uint4*)&dst[i] = o;
}

// ---------------------------------------------------------------------------
// QKV projection, bf16 MFMA, BK=64, full-DMA staging (R6-proven config).
// ---------------------------------------------------------------------------
__global__ __launch_bounds__(256, 3) void proj_mfma_kernel(
    const unsigned short* __restrict__ xb,
    const unsigned short* __restrict__ wq, const unsigned short* __restrict__ wk,
    const unsigned short* __restrict__ wv,
    unsigned short* __restrict__ qo, unsigned short* __restrict__ ko,
    unsigned short* __restrict__ vtg, float qscale)
{
    const unsigned short* W;
    if (blockIdx.z == 0)      W = wq;
    else if (blockIdx.z == 1) W = wk;
    else                      W = wv;

    __shared__ unsigned short smem[128 * 136];      // As(8192) Bs(8192) / Ts(17408)
    unsigned short* As = smem;
    unsigned short* Bs = smem + 8192;

    const int t = threadIdx.x;
    const int lane = t & 63, w = t >> 6;
    const int lq = lane >> 4, ln = lane & 15;
    const int m0 = blockIdx.y * 128, n0 = blockIdx.x * 128;
    const int wm = (w & 1) * 64, wn = (w >> 1) * 64;
    const int srow = t >> 3;                        // 0..31
    const int lsg  = ((t & 7) ^ ((t >> 3) & 7)) * 8;  // swizzled source seg*8
    const int key  = ln & 7;

    f32x4 acc[4][4];
    #pragma unroll
    for (int i = 0; i < 4; i++)
        #pragma unroll
        for (int j = 0; j < 4; j++) acc[i][j] = (f32x4){0.f,0.f,0.f,0.f};

    for (int c0 = 0; c0 < 512; c0 += 64) {
        __syncthreads();
        #pragma unroll
        for (int g = 0; g < 4; g++) {
            gload_lds16(&xb[(size_t)(m0 + 32*g + srow) * 512 + c0 + lsg], &As[(32*g + srow)*64 + (t&7)*8]);
            gload_lds16(&W [(size_t)(n0 + 32*g + srow) * 512 + c0 + lsg], &Bs[(32*g + srow)*64 + (t&7)*8]);
        }
        __syncthreads();

        #pragma unroll
        for (int kk = 0; kk < 2; kk++) {
            bf16x8 af[4], bf[4];
            #pragma unroll
            for (int i = 0; i < 4; i++)
                af[i] = *(bf16x8*)&As[(wm + 16*i + ln)*64 + ((kk*4 + lq) ^ key)*8];
            #pragma unroll
            for (int j = 0; j < 4; j++)
                bf[j] = *(bf16x8*)&Bs[(wn + 16*j + ln)*64 + ((kk*4 + lq) ^ key)*8];
            #pragma unroll
            for (int i = 0; i < 4; i++)
                #pragma unroll
                for (int j = 0; j < 4; j++)
                    acc[i][j] = __builtin_amdgcn_mfma_f32_16x16x32_bf16(af[i], bf[j], acc[i][j], 0, 0, 0);
        }
    }

    if (blockIdx.z < 2) {
        unsigned short* out = (blockIdx.z == 0) ? qo : ko;
        const float osc = (blockIdx.z == 0) ? qscale : 1.0f;
        #pragma unroll
        for (int i = 0; i < 4; i++) {
            #pragma unroll
            for (int r = 0; r < 4; r++) {
                int m = m0 + wm + 16*i + 4*lq + r;
                int b = m >> 10, l = m & 1023;
                #pragma unroll
                for (int j = 0; j < 4; j++) {
                    int n = n0 + wn + 16*j + ln;
                    int h = n >> 6, dh = n & 63;
                    out[((size_t)((b*Hc + h)*Lc + l))*DHc + dh] = f2bf(acc[i][j][r] * osc);
                }
            }
        }
    } else {
        // V: transpose through LDS, write V^T (B,H,DH,L)
        __syncthreads();
        unsigned short* Ts = smem;      // [n_local][m_local] stride 136
        #pragma unroll
        for (int i = 0; i < 4; i++) {
            int mlb = wm + 16*i + 4*lq;
            #pragma unroll
            for (int j = 0; j < 4; j++) {
                int nl = wn + 16*j + ln;
                *(uint2*)&Ts[nl*136 + mlb] = make_uint2(pk2(acc[i][j][0], acc[i][j][1]),
                                                        pk2(acc[i][j][2], acc[i][j][3]));
            }
        }
        __syncthreads();
        const int b = m0 >> 10, l0m = m0 & 1023;
        const int nl = t >> 1, seg = (t & 1) * 64;
        const int ng = n0 + nl, h = ng >> 6, dh = ng & 63;
        unsigned short* dst = vtg + (((size_t)(b*Hc + h))*DHc + dh)*Lc + l0m + seg;
        #pragma unroll
        for (int u = 0; u < 8; u++)
            *(uint4*)&dst[8*u] = *(uint4*)&Ts[nl*136 + seg + 8*u];
    }
}

// ---------------------------------------------------------------------------
// Output GEMM v13: 128x64 tiles (M x N), 512 blocks = 2/CU, proj-style
// staging (A: 4 DMA groups, B: 2). Per wave-iter: 12 b128 + 16 MFMA (was
// 8 + 8 at 64^2) -> better MFMA:LDS ratio, half the barriers per FLOP.
// out = awb @ Wo^T + bo (fp32 out).
// ---------------------------------------------------------------------------
__global__ __launch_bounds__(256, 2) void out_mfma_kernel(
    const unsigned short* __restrict__ A, const unsigned short* __restrict__ W,
    const float* __restrict__ bias, float* __restrict__ out)
{
    __shared__ unsigned short As[128 * 64];         // 16 KB
    __shared__ unsigned short Bs[64 * 64];          // 8 KB

    const int t = threadIdx.x;
    const int lane = t & 63, w = t >> 6;
    const int lq = lane >> 4, ln = lane & 15;
    const int m0 = blockIdx.y * 128, n0 = blockIdx.x * 64;
    const int wm = (w & 1) * 64, wn = (w >> 1) * 32;
    const int srow = t >> 3;                        // 0..31
    const int lsg  = ((t & 7) ^ ((t >> 3) & 7)) * 8;
    const int key  = ln & 7;

    f32x4 acc[4][2];
    #pragma unroll
    for (int i = 0; i < 4; i++)
        #pragma unroll
        for (int j = 0; j < 2; j++) acc[i][j] = (f32x4){0.f,0.f,0.f,0.f};

    for (int c0 = 0; c0 < 512; c0 += 64) {
        __syncthreads();
        #pragma unroll
        for (int g = 0; g < 4; g++)
            gload_lds16(&A[(size_t)(m0 + 32*g + srow) * 512 + c0 + lsg], &As[(32*g + srow)*64 + (t&7)*8]);
        #pragma unroll
        for (int g = 0; g < 2; g++)
            gload_lds16(&W[(size_t)(n0 + 32*g + srow) * 512 + c0 + lsg], &Bs[(32*g + srow)*64 + (t&7)*8]);
        __syncthreads();

        #pragma unroll
        for (int kk = 0; kk < 2; kk++) {
            bf16x8 af[4], bf[2];
            #pragma unroll
            for (int i = 0; i < 4; i++)
                af[i] = *(bf16x8*)&As[(wm + 16*i + ln)*64 + ((kk*4 + lq) ^ key)*8];
            #pragma unroll
            for (int j = 0; j < 2; j++)
                bf[j] = *(bf16x8*)&Bs[(wn + 16*j + ln)*64 + ((kk*4 + lq) ^ key)*8];
            #pragma unroll
            for (int i = 0; i < 4; i++)
                #pragma unroll
                for (int j = 0; j < 2; j++)
                    acc[i][j] = __builtin_amdgcn_mfma_f32_16x16x32_bf16(af[i], bf[j], acc[i][j], 0, 0, 0);
        }
    }

    float bb[2];
    #pragma unroll
    for (int j = 0; j < 2; j++) bb[j] = bias[n0 + wn + 16*j + ln];

    #pragma unroll
    for (int i = 0; i < 4; i++) {
        #pragma unroll
        for (int r = 0; r < 4; r++) {
            int m = m0 + wm + 16*i + 4*lq + r;
            #pragma unroll
            for (int j = 0; j < 2; j++) {
                int n = n0 + wn + 16*j + ln;
                out[(size_t)m * Dc + n] = acc[i][j][r] + bb[j];
            }
        }
    }
}

// ---------------------------------------------------------------------------
// attn v12 (UNCHANGED from R7 — control group this round): 32x32x16 MFMAs,
// in-register P exchange via v_permlane32_swap_b32, 3-barrier staggered DMA.
// ---------------------------------------------------------------------------
__global__ __launch_bounds__(256, 4) void attn_v12_kernel(
    const unsigned short* __restrict__ q, const unsigned short* __restrict__ k,
    const unsigned short* __restrict__ vtg, const unsigned short* __restrict__ wet,
    unsigned short* __restrict__ attn)
{
    __shared__ unsigned short smem[20480];          // 40960 B total
    unsigned short* ksp  = smem;                    // 8192 B  K     [s][dh swz]
    unsigned short* vtp  = smem + 4096;             // 8192 B  V^T   [dh][s swz]  (prologue: We pb0)
    unsigned short* wesp = smem + 8192;             // 8192 B  We    [e][dh swz]  (1 iter ahead)
    unsigned short* qes  = smem + 12288;            // 16384 B QE ring [slot][l^swz]

    const int t    = threadIdx.x;
    const int lane = t & 63, w = t >> 6;
    const int ln31 = lane & 31, hi = lane >> 5;
    const int si   = w >> 1;                        // s / e half: 0/1
    const int li   = w & 1;                         // l half: 0/1

    const int n   = blockIdx.x;
    const int xcd = n & 7, idx = n >> 3;
    const int bh  = xcd * 8 + (idx >> 4);
    const int l0  = (idx & 15) * 64;

    const unsigned short* qb  = q   + (size_t)bh * (Lc * DHc);
    const unsigned short* kb  = k   + (size_t)bh * (Lc * DHc);
    const unsigned short* vtb = vtg + (size_t)bh * (DHc * Lc);

    const int srow2 = t >> 3;                       // 0..31 staging row
    const int lsg2  = ((t & 7) ^ ((t >> 3) & 7)) * 8;
    const int k7    = ln31 & 7;
    const int lloc  = 32*li + ln31;

    // Q fragments (serve both A and B operand slots): Q[l][dh=16kk+8hi+j]
    bf16x8 qf[4];
    #pragma unroll
    for (int kk = 0; kk < 4; kk++)
        qf[kk] = *(const bf16x8*)&qb[(size_t)(l0 + lloc)*64 + kk*16 + hi*8];

    const int pb0 = 15 - (l0 >> 6);

    // prologue staging: panel pb0 -> vtp (scratch, pre-loop QE only),
    // panel pb0+1 (= newp of iter 0) -> wesp, K tile 0 -> ksp
    gload_lds16(&wet[(size_t)(64*pb0 + srow2)*64 + lsg2],        &vtp [t*8]);
    gload_lds16(&wet[(size_t)(64*pb0 + 32 + srow2)*64 + lsg2],   &vtp [2048 + t*8]);
    gload_lds16(&wet[(size_t)(64*(pb0+1) + srow2)*64 + lsg2],    &wesp[t*8]);
    gload_lds16(&wet[(size_t)(64*(pb0+1) + 32 + srow2)*64 + lsg2], &wesp[2048 + t*8]);
    gload_lds16(&kb [(size_t)srow2*64 + lsg2],                   &ksp [t*8]);
    gload_lds16(&kb [(size_t)(32 + srow2)*64 + lsg2],            &ksp [2048 + t*8]);
    __syncthreads();

    // pre-loop QE panel pb0 (from vtp scratch) -> ring
    {
        f32x16 qec = (f32x16){0.f,0.f,0.f,0.f,0.f,0.f,0.f,0.f,0.f,0.f,0.f,0.f,0.f,0.f,0.f,0.f};
        #pragma unroll
        for (int kk = 0; kk < 4; kk++) {
            bf16x8 wf = *(bf16x8*)&vtp[(32*si + ln31)*64 + ((2*kk + hi) ^ k7)*8];
            qec = __builtin_amdgcn_mfma_f32_32x32x16_bf16(qf[kk], wf, qec, 0, 0, 0);
        }
        const int rs = ((pb0 & 1)*64 + 32*si + ln31) * 64;
        #pragma unroll
        for (int g = 0; g < 4; g++) {
            const int col = (32*li + 8*g + 4*hi) ^ ((ln31 & 15) << 2);
            *(uint2*)&qes[rs + col] = make_uint2(pk2(qec[4*g], qec[4*g+1]),
                                                 pk2(qec[4*g+2], qec[4*g+3]));
        }
    }

    f32x16 Ov[2];
    #pragma unroll
    for (int dt = 0; dt < 2; dt++)
        Ov[dt] = (f32x16){0.f,0.f,0.f,0.f,0.f,0.f,0.f,0.f,0.f,0.f,0.f,0.f,0.f,0.f,0.f,0.f};
    float Lacc = 0.f;

    int pbOld = pb0 - 1;

    #pragma unroll 1
    for (int s0 = 0; s0 < Lc; s0 += 64) {
        const int c0  = l0 - s0;
        const int ac0 = c0 < 0 ? -c0 : c0;
        const int pb  = (960 - ac0) >> 6;
        const int newp = (pb > pbOld) ? pb + 1 : pb;
        pbOld = pb;
        const int cb = (newp & 1) * 64;
        const bool more = (s0 < Lc - 64);
        const int nc  = c0 - 64;
        const int nac = nc < 0 ? -nc : nc;
        const int npb = (960 - nac) >> 6;
        const int nnp = (npb > pb) ? npb + 1 : npb;   // newp of iter i+1

        __syncthreads();                            // B1: prev PV done (vtp free); ring writable; ksp(i) drained

        // vtp(i): drains at B2 under the QE phase; consumed at PV
        gload_lds16(&vtb[(size_t)srow2*1024 + s0 + lsg2],        &vtp[t*8]);
        gload_lds16(&vtb[(size_t)(32 + srow2)*1024 + s0 + lsg2], &vtp[2048 + t*8]);

        // ---- QE: panel newp from wesp (staged last iter) -> ring ----
        {
            f32x16 qec = (f32x16){0.f,0.f,0.f,0.f,0.f,0.f,0.f,0.f,0.f,0.f,0.f,0.f,0.f,0.f,0.f,0.f};
            #pragma unroll
            for (int kk = 0; kk < 4; kk++) {
                bf16x8 wf = *(bf16x8*)&wesp[(32*si + ln31)*64 + ((2*kk + hi) ^ k7)*8];
                qec = __builtin_amdgcn_mfma_f32_32x32x16_bf16(qf[kk], wf, qec, 0, 0, 0);
            }
            const int rs = (cb + 32*si + ln31) * 64;
            #pragma unroll
            for (int g = 0; g < 4; g++) {
                const int col = (32*li + 8*g + 4*hi) ^ ((ln31 & 15) << 2);
                *(uint2*)&qes[rs + col] = make_uint2(pk2(qec[4*g], qec[4*g+1]),
                                                     pk2(qec[4*g+2], qec[4*g+3]));
            }
        }

        __syncthreads();                            // B2: ring visible; vtp drained; wesp free

        // wesp(i+1): drains at B3 under the QK+bias phase
        if (more) {
            gload_lds16(&wet[(size_t)(64*nnp + srow2)*64 + lsg2],      &wesp[t*8]);
            gload_lds16(&wet[(size_t)(64*nnp + 32 + srow2)*64 + lsg2], &wesp[2048 + t*8]);
        }

        // ---- S^T = mfma(K, Q): rows s = (reg&3)+8(reg>>2)+4hi + 32si, col l = lloc
        f32x16 sc = (f32x16){0.f,0.f,0.f,0.f,0.f,0.f,0.f,0.f,0.f,0.f,0.f,0.f,0.f,0.f,0.f,0.f};
        #pragma unroll
        for (int kk = 0; kk < 4; kk++) {
            bf16x8 kf = *(bf16x8*)&ksp[(32*si + ln31)*64 + ((2*kk + hi) ^ k7)*8];
            sc = __builtin_amdgcn_mfma_f32_32x32x16_bf16(kf, qf[kk], sc, 0, 0, 0);
        }

        // ---- bias + exp2; pack P; in-register exchange -> PV B-frags ----
        float p[16];
        #pragma unroll
        for (int g = 0; g < 4; g++) {
            const int sb = 32*si + 8*g + 4*hi;
            #pragma unroll
            for (int r = 0; r < 4; r++) {
                int d  = c0 + lloc - sb - r;
                int ad = d < 0 ? -d : d;
                int m  = 1023 - ad;
                float bias = bf2f(qes[(m & 127)*64 + (lloc ^ ((m & 15) << 2))]);
                p[4*g + r] = __builtin_amdgcn_exp2f(sc[4*g + r] + bias);
            }
        }
        // Lacc partial (this lane's 16 s-rows for its l)
        {
            float t0 = (p[0]+p[1]) + (p[2]+p[3]);
            float t1 = (p[4]+p[5]) + (p[6]+p[7]);
            float t2 = (p[8]+p[9]) + (p[10]+p[11]);
            float t3 = (p[12]+p[13]) + (p[14]+p[15]);
            Lacc += (t0 + t1) + (t2 + t3);
        }
        unsigned d0[4], d1[4];
        #pragma unroll
        for (int g = 0; g < 4; g++) {
            d0[g] = pk2t(p[4*g],     p[4*g + 1]);
            d1[g] = pk2t(p[4*g + 2], p[4*g + 3]);
        }
        bf16x8 pfr[2];
        #pragma unroll
        for (int kk = 0; kk < 2; kk++) {
            pl32swap(d0[2*kk], d0[2*kk + 1]);
            pl32swap(d1[2*kk], d1[2*kk + 1]);
            uint4 fu = make_uint4(d0[2*kk], d1[2*kk], d0[2*kk + 1], d1[2*kk + 1]);
            pfr[kk] = *(bf16x8*)&fu;
        }

        __syncthreads();                            // B3: ksp free (QK done); ring reads done; wesp(i+1) drained

        // ksp(i+1): drains at next B1 under the PV phase
        if (more) {
            gload_lds16(&kb[(size_t)(s0 + 64 + srow2)*64 + lsg2],      &ksp[t*8]);
            gload_lds16(&kb[(size_t)(s0 + 64 + 32 + srow2)*64 + lsg2], &ksp[2048 + t*8]);
        }

        // ---- O^T += mfma(V^T, P^T) over this wave's s-half ----
        #pragma unroll
        for (int kk = 0; kk < 2; kk++)
            #pragma unroll
            for (int dt = 0; dt < 2; dt++) {
                bf16x8 vf = *(bf16x8*)&vtp[(32*dt + ln31)*64 + (((4*si + 2*kk + hi) ^ k7))*8];
                Ov[dt] = __builtin_amdgcn_mfma_f32_32x32x16_bf16(vf, pfr[kk], Ov[dt], 0, 0, 0);
            }
    }

    // ---- epilogue: hi-merge Lacc, cross-si reduce via LDS, normalize, store
    unsigned la = __float_as_uint(Lacc), lb = la;
    pl32swap(la, lb);
    float Lh = Lacc + __uint_as_float(hi ? la : lb);   // full si-half denominator

    __syncthreads();
    float* scr = (float*)smem;                       // 33*128 f32 = 16.9 KB
    if (si == 1) {
        #pragma unroll
        for (int dt = 0; dt < 2; dt++)
            #pragma unroll
            for (int rg = 0; rg < 16; rg++)
                scr[(dt*16 + rg)*128 + li*64 + lane] = Ov[dt][rg];
        scr[32*128 + li*64 + lane] = Lh;
    }
    __syncthreads();
    if (si == 0) {
        const float Lt = Lh + scr[32*128 + li*64 + lane];
        const float inv = 1.f / Lt;
        const int b = bh >> 3, h = bh & 7;
        const int lg = l0 + lloc;
        unsigned short* dst = attn + ((size_t)(b*Lc + lg))*Dc + h*DHc;
        #pragma unroll
        for (int dt = 0; dt < 2; dt++)
            #pragma unroll
            for (int g = 0; g < 4; g++) {
                float v0 = (Ov[dt][4*g]   + scr[(dt*16 + 4*g)*128 + li*64 + lane]) * inv;
                float v1 = (Ov[dt][4*g+1] + scr[(dt*16 + 4*g+1)*128 + li*64 + lane]) * inv;
                float v2 = (Ov[dt][4*g+2] + scr[(dt*16 + 4*g+2)*128 + li*64 + lane]) * inv;
                float v3 = (Ov[dt][4*g+3] + scr[(dt*16 + 4*g+3)*128 + li*64 + lane]) * inv;
                *(uint2*)&dst[32*dt + 8*g + 4*hi] = make_uint2(pk2(v0, v1), pk2(v2, v3));
            }
    }
}

extern "C" void kernel_launch(void* const* d_in, const int* in_sizes, int n_in,
                              void* d_out, int out_size, void* d_ws, size_t ws_size,
                              hipStream_t stream)
{
    (void)in_sizes; (void)n_in; (void)out_size; (void)ws_size;
    const float* x  = (const float*)d_in[0];
    const float* Wq = (const float*)d_in[1];
    const float* Wk = (const float*)d_in[2];
    const float* Wv = (const float*)d_in[3];
    const float* We = (const float*)d_in[4];
    const float* Wo = (const float*)d_in[5];
    const float* bo = (const float*)d_in[6];

    const size_t NT = (size_t)8 * Hc * Lc * DHc;     // 4,194,304 elems
    unsigned short* qw  = (unsigned short*)d_ws;
    unsigned short* kw  = qw  + NT;
    unsigned short* vtg = kw  + NT;                  // V^T (B,H,DH,L)
    unsigned short* xbf = vtg + NT;
    unsigned short* awb = xbf + NT;                  // attn out bf16 (B,L,D)
    unsigned short* wqb = awb + NT;
    unsigned short* wkb = wqb + 262144;
    unsigned short* wvb = wkb + 262144;
    unsigned short* wob = wvb + 262144;
    unsigned short* wet = wob + 262144;              // 65536 + 4096 pad (panel-16 DMA overread)

    cvt_all_kernel<<<2592, 256, 0, stream>>>(x, Wq, Wk, Wv, Wo, We,
                                             xbf, wqb, wkb, wvb, wob, wet);
    proj_mfma_kernel<<<dim3(4, 64, 3), 256, 0, stream>>>(xbf, wqb, wkb, wvb,
                                                         qw, kw, vtg,
                                                         0.125f * 1.44269504089f);
    attn_v12_kernel<<<1024, 256, 0, stream>>>(qw, kw, vtg, wet, awb);
    out_mfma_kernel<<<dim3(8, 64), 256, 0, stream>>>(awb, wob, bo, (float*)d_out);
}

// Round 9
// 162.613 us; speedup vs baseline: 1.1605x; 1.0277x over previous
//
#include <hip/hip_runtime.h>

#define Lc 1024
#define Dc 512
#define Hc 8
#define DHc 64

typedef __attribute__((ext_vector_type(8))) short bf16x8;
typedef __attribute__((ext_vector_type(4))) float f32x4;
typedef __attribute__((ext_vector_type(16))) float f32x16;

typedef __attribute__((address_space(1))) const unsigned int guint;
typedef __attribute__((address_space(3))) unsigned int luint;

__device__ __forceinline__ void gload_lds16(const void* g, void* l) {
    __builtin_amdgcn_global_load_lds((guint*)g, (luint*)l, 16, 0, 0);
}

__device__ __forceinline__ unsigned short f2bf(float f) {
    unsigned u = __float_as_uint(f);
    u += 0x7fffu + ((u >> 16) & 1u);          // round-to-nearest-even
    return (unsigned short)(u >> 16);
}
__device__ __forceinline__ unsigned pk2(float a, float b) {
    return (unsigned)f2bf(a) | ((unsigned)f2bf(b) << 16);
}
__device__ __forceinline__ unsigned pk2t(float a, float b) {   // truncating pack, 1 v_perm
    return __builtin_amdgcn_perm(__float_as_uint(b), __float_as_uint(a), 0x07060302u);
}
__device__ __forceinline__ float bf2f(unsigned short s) { return __uint_as_float(((unsigned)s) << 16); }

// v_permlane32_swap_b32: a' = {a.lo, b.lo}; b' = {a.hi, b.hi}
__device__ __forceinline__ void pl32swap(unsigned &a, unsigned &b) {
    asm volatile("v_permlane32_swap_b32 %0, %1" : "+v"(a), "+v"(b));
}
// ({hi:lo} >> sh)[31:0], sh may be per-lane VGPR
__device__ __forceinline__ unsigned alignbit(unsigned hi, unsigned lo, unsigned sh) {
    unsigned d;
    asm("v_alignbit_b32 %0, %1, %2, %3" : "=v"(d) : "v"(hi), "v"(lo), "v"(sh));
    return d;
}

// ---------------------------------------------------------------------------
// fp32 -> bf16 cast of x, Wq, Wk, Wv, Wo, We.
// ---------------------------------------------------------------------------
__global__ void cvt_all_kernel(
    const float* __restrict__ x,  const float* __restrict__ Wq,
    const float* __restrict__ Wk, const float* __restrict__ Wv,
    const float* __restrict__ Wo, const float* __restrict__ We,
    unsigned short* __restrict__ xb,  unsigned short* __restrict__ wqb,
    unsigned short* __restrict__ wkb, unsigned short* __restrict__ wvb,
    unsigned short* __restrict__ wob, unsigned short* __restrict__ wet)
{
    int bid = blockIdx.x;
    const float* src; unsigned short* dst; size_t base;
    if      (bid < 2048) { src = x;  dst = xb;  base = (size_t)bid * 2048; }
    else if (bid < 2176) { src = Wq; dst = wqb; base = (size_t)(bid-2048) * 2048; }
    else if (bid < 2304) { src = Wk; dst = wkb; base = (size_t)(bid-2176) * 2048; }
    else if (bid < 2432) { src = Wv; dst = wvb; base = (size_t)(bid-2304) * 2048; }
    else if (bid < 2560) { src = Wo; dst = wob; base = (size_t)(bid-2432) * 2048; }
    else                 { src = We; dst = wet; base = (size_t)(bid-2560) * 2048; }
    size_t i = base + (size_t)threadIdx.x * 8;
    float4 a = *(const float4*)&src[i];
    float4 b = *(const float4*)&src[i + 4];
    uint4 o = make_uint4(pk2(a.x, a.y), pk2(a.z, a.w), pk2(b.x, b.y), pk2(b.z, b.w));
    *(uint4*)&dst[i] = o;
}

// ---------------------------------------------------------------------------
// QKV projection, bf16 MFMA, BK=64, full-DMA staging (R6-proven config).
// ---------------------------------------------------------------------------
__global__ __launch_bounds__(256, 3) void proj_mfma_kernel(
    const unsigned short* __restrict__ xb,
    const unsigned short* __restrict__ wq, const unsigned short* __restrict__ wk,
    const unsigned short* __restrict__ wv,
    unsigned short* __restrict__ qo, unsigned short* __restrict__ ko,
    unsigned short* __restrict__ vtg, float qscale)
{
    const unsigned short* W;
    if (blockIdx.z == 0)      W = wq;
    else if (blockIdx.z == 1) W = wk;
    else                      W = wv;

    __shared__ unsigned short smem[128 * 136];      // As(8192) Bs(8192) / Ts(17408)
    unsigned short* As = smem;
    unsigned short* Bs = smem + 8192;

    const int t = threadIdx.x;
    const int lane = t & 63, w = t >> 6;
    const int lq = lane >> 4, ln = lane & 15;
    const int m0 = blockIdx.y * 128, n0 = blockIdx.x * 128;
    const int wm = (w & 1) * 64, wn = (w >> 1) * 64;
    const int srow = t >> 3;                        // 0..31
    const int lsg  = ((t & 7) ^ ((t >> 3) & 7)) * 8;  // swizzled source seg*8
    const int key  = ln & 7;

    f32x4 acc[4][4];
    #pragma unroll
    for (int i = 0; i < 4; i++)
        #pragma unroll
        for (int j = 0; j < 4; j++) acc[i][j] = (f32x4){0.f,0.f,0.f,0.f};

    for (int c0 = 0; c0 < 512; c0 += 64) {
        __syncthreads();
        #pragma unroll
        for (int g = 0; g < 4; g++) {
            gload_lds16(&xb[(size_t)(m0 + 32*g + srow) * 512 + c0 + lsg], &As[(32*g + srow)*64 + (t&7)*8]);
            gload_lds16(&W [(size_t)(n0 + 32*g + srow) * 512 + c0 + lsg], &Bs[(32*g + srow)*64 + (t&7)*8]);
        }
        __syncthreads();

        #pragma unroll
        for (int kk = 0; kk < 2; kk++) {
            bf16x8 af[4], bf[4];
            #pragma unroll
            for (int i = 0; i < 4; i++)
                af[i] = *(bf16x8*)&As[(wm + 16*i + ln)*64 + ((kk*4 + lq) ^ key)*8];
            #pragma unroll
            for (int j = 0; j < 4; j++)
                bf[j] = *(bf16x8*)&Bs[(wn + 16*j + ln)*64 + ((kk*4 + lq) ^ key)*8];
            #pragma unroll
            for (int i = 0; i < 4; i++)
                #pragma unroll
                for (int j = 0; j < 4; j++)
                    acc[i][j] = __builtin_amdgcn_mfma_f32_16x16x32_bf16(af[i], bf[j], acc[i][j], 0, 0, 0);
        }
    }

    if (blockIdx.z < 2) {
        unsigned short* out = (blockIdx.z == 0) ? qo : ko;
        const float osc = (blockIdx.z == 0) ? qscale : 1.0f;
        #pragma unroll
        for (int i = 0; i < 4; i++) {
            #pragma unroll
            for (int r = 0; r < 4; r++) {
                int m = m0 + wm + 16*i + 4*lq + r;
                int b = m >> 10, l = m & 1023;
                #pragma unroll
                for (int j = 0; j < 4; j++) {
                    int n = n0 + wn + 16*j + ln;
                    int h = n >> 6, dh = n & 63;
                    out[((size_t)((b*Hc + h)*Lc + l))*DHc + dh] = f2bf(acc[i][j][r] * osc);
                }
            }
        }
    } else {
        // V: transpose through LDS, write V^T (B,H,DH,L)
        __syncthreads();
        unsigned short* Ts = smem;      // [n_local][m_local] stride 136
        #pragma unroll
        for (int i = 0; i < 4; i++) {
            int mlb = wm + 16*i + 4*lq;
            #pragma unroll
            for (int j = 0; j < 4; j++) {
                int nl = wn + 16*j + ln;
                *(uint2*)&Ts[nl*136 + mlb] = make_uint2(pk2(acc[i][j][0], acc[i][j][1]),
                                                        pk2(acc[i][j][2], acc[i][j][3]));
            }
        }
        __syncthreads();
        const int b = m0 >> 10, l0m = m0 & 1023;
        const int nl = t >> 1, seg = (t & 1) * 64;
        const int ng = n0 + nl, h = ng >> 6, dh = ng & 63;
        unsigned short* dst = vtg + (((size_t)(b*Hc + h))*DHc + dh)*Lc + l0m + seg;
        #pragma unroll
        for (int u = 0; u < 8; u++)
            *(uint4*)&dst[8*u] = *(uint4*)&Ts[nl*136 + seg + 8*u];
    }
}

// ---------------------------------------------------------------------------
// Output GEMM: 128x64 tiles, 512 blocks = 2/CU (unchanged from R8).
// ---------------------------------------------------------------------------
__global__ __launch_bounds__(256, 2) void out_mfma_kernel(
    const unsigned short* __restrict__ A, const unsigned short* __restrict__ W,
    const float* __restrict__ bias, float* __restrict__ out)
{
    __shared__ unsigned short As[128 * 64];         // 16 KB
    __shared__ unsigned short Bs[64 * 64];          // 8 KB

    const int t = threadIdx.x;
    const int lane = t & 63, w = t >> 6;
    const int lq = lane >> 4, ln = lane & 15;
    const int m0 = blockIdx.y * 128, n0 = blockIdx.x * 64;
    const int wm = (w & 1) * 64, wn = (w >> 1) * 32;
    const int srow = t >> 3;                        // 0..31
    const int lsg  = ((t & 7) ^ ((t >> 3) & 7)) * 8;
    const int key  = ln & 7;

    f32x4 acc[4][2];
    #pragma unroll
    for (int i = 0; i < 4; i++)
        #pragma unroll
        for (int j = 0; j < 2; j++) acc[i][j] = (f32x4){0.f,0.f,0.f,0.f};

    for (int c0 = 0; c0 < 512; c0 += 64) {
        __syncthreads();
        #pragma unroll
        for (int g = 0; g < 4; g++)
            gload_lds16(&A[(size_t)(m0 + 32*g + srow) * 512 + c0 + lsg], &As[(32*g + srow)*64 + (t&7)*8]);
        #pragma unroll
        for (int g = 0; g < 2; g++)
            gload_lds16(&W[(size_t)(n0 + 32*g + srow) * 512 + c0 + lsg], &Bs[(32*g + srow)*64 + (t&7)*8]);
        __syncthreads();

        #pragma unroll
        for (int kk = 0; kk < 2; kk++) {
            bf16x8 af[4], bf[2];
            #pragma unroll
            for (int i = 0; i < 4; i++)
                af[i] = *(bf16x8*)&As[(wm + 16*i + ln)*64 + ((kk*4 + lq) ^ key)*8];
            #pragma unroll
            for (int j = 0; j < 2; j++)
                bf[j] = *(bf16x8*)&Bs[(wn + 16*j + ln)*64 + ((kk*4 + lq) ^ key)*8];
            #pragma unroll
            for (int i = 0; i < 4; i++)
                #pragma unroll
                for (int j = 0; j < 2; j++)
                    acc[i][j] = __builtin_amdgcn_mfma_f32_16x16x32_bf16(af[i], bf[j], acc[i][j], 0, 0, 0);
        }
    }

    float bb[2];
    #pragma unroll
    for (int j = 0; j < 2; j++) bb[j] = bias[n0 + wn + 16*j + ln];

    #pragma unroll
    for (int i = 0; i < 4; i++) {
        #pragma unroll
        for (int r = 0; r < 4; r++) {
            int m = m0 + wm + 16*i + 4*lq + r;
            #pragma unroll
            for (int j = 0; j < 2; j++) {
                int n = n0 + wn + 16*j + ln;
                out[(size_t)m * Dc + n] = acc[i][j][r] + bb[j];
            }
        }
    }
}

// ---------------------------------------------------------------------------
// attn v13: v12 + transposed QE ring [l][slot] (XOR swizzle col^=(l&15)<<2).
//  - QE mfma operands swapped (wf as A): reg-index = e -> ring writes stay
//    uint2-packed in the transposed layout (fragments are layout-identical)
//  - bias gather: 4 consecutive slots per g -> 2 aligned ds_read_b64 +
//    v_alignbit extraction; asc (c0>=128) / desc (c0<=-64) under UNIFORM
//    branch; scalar fallback only for the 2 boundary iters (c0 in {0,64})
//  - everything else (staging schedule, QK, P-swap, PV, epilogue) unchanged
// ---------------------------------------------------------------------------
__global__ __launch_bounds__(256, 4) void attn_v13_kernel(
    const unsigned short* __restrict__ q, const unsigned short* __restrict__ k,
    const unsigned short* __restrict__ vtg, const unsigned short* __restrict__ wet,
    unsigned short* __restrict__ attn)
{
    __shared__ unsigned short smem[20480];          // 40960 B total
    unsigned short* ksp  = smem;                    // 8192 B  K     [s][dh swz]
    unsigned short* vtp  = smem + 4096;             // 8192 B  V^T   [dh][s swz]  (prologue: We pb0)
    unsigned short* wesp = smem + 8192;             // 8192 B  We    [e][dh swz]  (1 iter ahead)
    unsigned short* qes  = smem + 12288;            // 16384 B QE ring TRANSPOSED [l][slot^swz]

    const int t    = threadIdx.x;
    const int lane = t & 63, w = t >> 6;
    const int ln31 = lane & 31, hi = lane >> 5;
    const int si   = w >> 1;                        // s / e half: 0/1
    const int li   = w & 1;                         // l half: 0/1

    const int n   = blockIdx.x;
    const int xcd = n & 7, idx = n >> 3;
    const int bh  = xcd * 8 + (idx >> 4);
    const int l0  = (idx & 15) * 64;

    const unsigned short* qb  = q   + (size_t)bh * (Lc * DHc);
    const unsigned short* kb  = k   + (size_t)bh * (Lc * DHc);
    const unsigned short* vtb = vtg + (size_t)bh * (DHc * Lc);

    const int srow2 = t >> 3;                       // 0..31 staging row
    const int lsg2  = ((t & 7) ^ ((t >> 3) & 7)) * 8;
    const int k7    = ln31 & 7;
    const int lloc  = 32*li + ln31;
    const int wkey  = (lloc & 15) << 2;             // ring col swizzle (bits 2-5)
    unsigned short* qrow = &qes[lloc * 128];

    // Q fragments (serve both A and B operand slots): Q[l][dh=16kk+8hi+j]
    bf16x8 qf[4];
    #pragma unroll
    for (int kk = 0; kk < 4; kk++)
        qf[kk] = *(const bf16x8*)&qb[(size_t)(l0 + lloc)*64 + kk*16 + hi*8];

    const int pb0 = 15 - (l0 >> 6);

    // prologue staging: panel pb0 -> vtp (scratch, pre-loop QE only),
    // panel pb0+1 (= newp of iter 0) -> wesp, K tile 0 -> ksp
    gload_lds16(&wet[(size_t)(64*pb0 + srow2)*64 + lsg2],        &vtp [t*8]);
    gload_lds16(&wet[(size_t)(64*pb0 + 32 + srow2)*64 + lsg2],   &vtp [2048 + t*8]);
    gload_lds16(&wet[(size_t)(64*(pb0+1) + srow2)*64 + lsg2],    &wesp[t*8]);
    gload_lds16(&wet[(size_t)(64*(pb0+1) + 32 + srow2)*64 + lsg2], &wesp[2048 + t*8]);
    gload_lds16(&kb [(size_t)srow2*64 + lsg2],                   &ksp [t*8]);
    gload_lds16(&kb [(size_t)(32 + srow2)*64 + lsg2],            &ksp [2048 + t*8]);
    __syncthreads();

    // pre-loop QE panel pb0 (from vtp scratch) -> transposed ring
    {
        f32x16 qec = (f32x16){0.f,0.f,0.f,0.f,0.f,0.f,0.f,0.f,0.f,0.f,0.f,0.f,0.f,0.f,0.f,0.f};
        #pragma unroll
        for (int kk = 0; kk < 4; kk++) {
            bf16x8 wf = *(bf16x8*)&vtp[(32*si + ln31)*64 + ((2*kk + hi) ^ k7)*8];
            qec = __builtin_amdgcn_mfma_f32_32x32x16_bf16(wf, qf[kk], qec, 0, 0, 0);
        }
        const int cb = (pb0 & 1) * 64;
        #pragma unroll
        for (int g = 0; g < 4; g++) {
            const int col = (cb + 32*si + 8*g + 4*hi) ^ wkey;
            *(uint2*)&qrow[col] = make_uint2(pk2(qec[4*g], qec[4*g+1]),
                                             pk2(qec[4*g+2], qec[4*g+3]));
        }
    }

    f32x16 Ov[2];
    #pragma unroll
    for (int dt = 0; dt < 2; dt++)
        Ov[dt] = (f32x16){0.f,0.f,0.f,0.f,0.f,0.f,0.f,0.f,0.f,0.f,0.f,0.f,0.f,0.f,0.f,0.f};
    float Lacc = 0.f;

    int pbOld = pb0 - 1;

    #pragma unroll 1
    for (int s0 = 0; s0 < Lc; s0 += 64) {
        const int c0  = l0 - s0;
        const int ac0 = c0 < 0 ? -c0 : c0;
        const int pb  = (960 - ac0) >> 6;
        const int newp = (pb > pbOld) ? pb + 1 : pb;
        pbOld = pb;
        const int cb = (newp & 1) * 64;
        const bool more = (s0 < Lc - 64);
        const int nc  = c0 - 64;
        const int nac = nc < 0 ? -nc : nc;
        const int npb = (960 - nac) >> 6;
        const int nnp = (npb > pb) ? npb + 1 : npb;   // newp of iter i+1

        __syncthreads();                            // B1: prev PV done; ring writable; ksp(i) drained

        // vtp(i): drains at B2 under the QE phase; consumed at PV
        gload_lds16(&vtb[(size_t)srow2*1024 + s0 + lsg2],        &vtp[t*8]);
        gload_lds16(&vtb[(size_t)(32 + srow2)*1024 + s0 + lsg2], &vtp[2048 + t*8]);

        // ---- QE: panel newp from wesp -> transposed ring ----
        {
            f32x16 qec = (f32x16){0.f,0.f,0.f,0.f,0.f,0.f,0.f,0.f,0.f,0.f,0.f,0.f,0.f,0.f,0.f,0.f};
            #pragma unroll
            for (int kk = 0; kk < 4; kk++) {
                bf16x8 wf = *(bf16x8*)&wesp[(32*si + ln31)*64 + ((2*kk + hi) ^ k7)*8];
                qec = __builtin_amdgcn_mfma_f32_32x32x16_bf16(wf, qf[kk], qec, 0, 0, 0);
            }
            #pragma unroll
            for (int g = 0; g < 4; g++) {
                const int col = (cb + 32*si + 8*g + 4*hi) ^ wkey;
                *(uint2*)&qrow[col] = make_uint2(pk2(qec[4*g], qec[4*g+1]),
                                                 pk2(qec[4*g+2], qec[4*g+3]));
            }
        }

        __syncthreads();                            // B2: ring visible; vtp drained; wesp free

        // wesp(i+1): drains at B3 under the QK+bias phase
        if (more) {
            gload_lds16(&wet[(size_t)(64*nnp + srow2)*64 + lsg2],      &wesp[t*8]);
            gload_lds16(&wet[(size_t)(64*nnp + 32 + srow2)*64 + lsg2], &wesp[2048 + t*8]);
        }

        // ---- S^T = mfma(K, Q): rows s = (reg&3)+8(reg>>2)+4hi + 32si, col l = lloc
        f32x16 sc = (f32x16){0.f,0.f,0.f,0.f,0.f,0.f,0.f,0.f,0.f,0.f,0.f,0.f,0.f,0.f,0.f,0.f};
        #pragma unroll
        for (int kk = 0; kk < 4; kk++) {
            bf16x8 kf = *(bf16x8*)&ksp[(32*si + ln31)*64 + ((2*kk + hi) ^ k7)*8];
            sc = __builtin_amdgcn_mfma_f32_32x32x16_bf16(kf, qf[kk], sc, 0, 0, 0);
        }

        // ---- bias gather + exp2 ----
        float p[16];
        if (c0 >= 128 || c0 <= -64) {
            const bool asc = (c0 >= 128);
            #pragma unroll
            for (int g = 0; g < 4; g++) {
                const int dbase0 = c0 + lloc - (32*si + 8*g + 4*hi);
                const int base = asc ? (1023 - dbase0) : (1020 + dbase0);
                const int a  = (base & ~3) & 127;
                const int a2 = (a + 4) & 127;
                const uint2 w01 = *(const uint2*)&qrow[a  ^ wkey];   // q0..q3
                const uint2 w23 = *(const uint2*)&qrow[a2 ^ wkey];   // q4..q7
                const int off = base & 3;
                const bool oh = (off >= 2);
                const unsigned wl = oh ? w01.y : w01.x;
                const unsigned wm = oh ? w23.x : w01.y;
                const unsigned wh = oh ? w23.y : w23.x;
                const unsigned sh = (unsigned)(off & 1) * 16u;
                const unsigned r0 = alignbit(wm, wl, sh);            // q_off, q_off+1
                const unsigned r1 = alignbit(wh, wm, sh);            // q_off+2, q_off+3
                float b0, b1, b2, b3;
                if (asc) {
                    b0 = __uint_as_float(r0 << 16);
                    b1 = __uint_as_float(r0 & 0xffff0000u);
                    b2 = __uint_as_float(r1 << 16);
                    b3 = __uint_as_float(r1 & 0xffff0000u);
                } else {                                             // reversed
                    b0 = __uint_as_float(r1 & 0xffff0000u);
                    b1 = __uint_as_float(r1 << 16);
                    b2 = __uint_as_float(r0 & 0xffff0000u);
                    b3 = __uint_as_float(r0 << 16);
                }
                p[4*g+0] = __builtin_amdgcn_exp2f(sc[4*g+0] + b0);
                p[4*g+1] = __builtin_amdgcn_exp2f(sc[4*g+1] + b1);
                p[4*g+2] = __builtin_amdgcn_exp2f(sc[4*g+2] + b2);
                p[4*g+3] = __builtin_amdgcn_exp2f(sc[4*g+3] + b3);
            }
        } else {                                    // c0 in {0, 64}: scalar fallback
            #pragma unroll
            for (int g = 0; g < 4; g++) {
                const int sb = 32*si + 8*g + 4*hi;
                #pragma unroll
                for (int r = 0; r < 4; r++) {
                    int d  = c0 + lloc - sb - r;
                    int ad = d < 0 ? -d : d;
                    int m  = 1023 - ad;
                    float bias = bf2f(qrow[(m & 127) ^ wkey]);
                    p[4*g + r] = __builtin_amdgcn_exp2f(sc[4*g + r] + bias);
                }
            }
        }

        // Lacc partial (this lane's 16 s-rows for its l)
        {
            float t0 = (p[0]+p[1]) + (p[2]+p[3]);
            float t1 = (p[4]+p[5]) + (p[6]+p[7]);
            float t2 = (p[8]+p[9]) + (p[10]+p[11]);
            float t3 = (p[12]+p[13]) + (p[14]+p[15]);
            Lacc += (t0 + t1) + (t2 + t3);
        }
        unsigned d0[4], d1[4];
        #pragma unroll
        for (int g = 0; g < 4; g++) {
            d0[g] = pk2t(p[4*g],     p[4*g + 1]);
            d1[g] = pk2t(p[4*g + 2], p[4*g + 3]);
        }
        bf16x8 pfr[2];
        #pragma unroll
        for (int kk = 0; kk < 2; kk++) {
            pl32swap(d0[2*kk], d0[2*kk + 1]);
            pl32swap(d1[2*kk], d1[2*kk + 1]);
            uint4 fu = make_uint4(d0[2*kk], d1[2*kk], d0[2*kk + 1], d1[2*kk + 1]);
            pfr[kk] = *(bf16x8*)&fu;
        }

        __syncthreads();                            // B3: ksp free; ring reads done; wesp(i+1) drained

        // ksp(i+1): drains at next B1 under the PV phase
        if (more) {
            gload_lds16(&kb[(size_t)(s0 + 64 + srow2)*64 + lsg2],      &ksp[t*8]);
            gload_lds16(&kb[(size_t)(s0 + 64 + 32 + srow2)*64 + lsg2], &ksp[2048 + t*8]);
        }

        // ---- O^T += mfma(V^T, P^T) over this wave's s-half ----
        #pragma unroll
        for (int kk = 0; kk < 2; kk++)
            #pragma unroll
            for (int dt = 0; dt < 2; dt++) {
                bf16x8 vf = *(bf16x8*)&vtp[(32*dt + ln31)*64 + (((4*si + 2*kk + hi) ^ k7))*8];
                Ov[dt] = __builtin_amdgcn_mfma_f32_32x32x16_bf16(vf, pfr[kk], Ov[dt], 0, 0, 0);
            }
    }

    // ---- epilogue: hi-merge Lacc, cross-si reduce via LDS, normalize, store
    unsigned la = __float_as_uint(Lacc), lb = la;
    pl32swap(la, lb);
    float Lh = Lacc + __uint_as_float(hi ? la : lb);   // full si-half denominator

    __syncthreads();
    float* scr = (float*)smem;                       // 33*128 f32 = 16.9 KB
    if (si == 1) {
        #pragma unroll
        for (int dt = 0; dt < 2; dt++)
            #pragma unroll
            for (int rg = 0; rg < 16; rg++)
                scr[(dt*16 + rg)*128 + li*64 + lane] = Ov[dt][rg];
        scr[32*128 + li*64 + lane] = Lh;
    }
    __syncthreads();
    if (si == 0) {
        const float Lt = Lh + scr[32*128 + li*64 + lane];
        const float inv = 1.f / Lt;
        const int b = bh >> 3, h = bh & 7;
        const int lg = l0 + lloc;
        unsigned short* dst = attn + ((size_t)(b*Lc + lg))*Dc + h*DHc;
        #pragma unroll
        for (int dt = 0; dt < 2; dt++)
            #pragma unroll
            for (int g = 0; g < 4; g++) {
                float v0 = (Ov[dt][4*g]   + scr[(dt*16 + 4*g)*128 + li*64 + lane]) * inv;
                float v1 = (Ov[dt][4*g+1] + scr[(dt*16 + 4*g+1)*128 + li*64 + lane]) * inv;
                float v2 = (Ov[dt][4*g+2] + scr[(dt*16 + 4*g+2)*128 + li*64 + lane]) * inv;
                float v3 = (Ov[dt][4*g+3] + scr[(dt*16 + 4*g+3)*128 + li*64 + lane]) * inv;
                *(uint2*)&dst[32*dt + 8*g + 4*hi] = make_uint2(pk2(v0, v1), pk2(v2, v3));
            }
    }
}

extern "C" void kernel_launch(void* const* d_in, const int* in_sizes, int n_in,
                              void* d_out, int out_size, void* d_ws, size_t ws_size,
                              hipStream_t stream)
{
    (void)in_sizes; (void)n_in; (void)out_size; (void)ws_size;
    const float* x  = (const float*)d_in[0];
    const float* Wq = (const float*)d_in[1];
    const float* Wk = (const float*)d_in[2];
    const float* Wv = (const float*)d_in[3];
    const float* We = (const float*)d_in[4];
    const float* Wo = (const float*)d_in[5];
    const float* bo = (const float*)d_in[6];

    const size_t NT = (size_t)8 * Hc * Lc * DHc;     // 4,194,304 elems
    unsigned short* qw  = (unsigned short*)d_ws;
    unsigned short* kw  = qw  + NT;
    unsigned short* vtg = kw  + NT;                  // V^T (B,H,DH,L)
    unsigned short* xbf = vtg + NT;
    unsigned short* awb = xbf + NT;                  // attn out bf16 (B,L,D)
    unsigned short* wqb = awb + NT;
    unsigned short* wkb = wqb + 262144;
    unsigned short* wvb = wkb + 262144;
    unsigned short* wob = wvb + 262144;
    unsigned short* wet = wob + 262144;              // 65536 + 4096 pad (panel-16 DMA overread)

    cvt_all_kernel<<<2592, 256, 0, stream>>>(x, Wq, Wk, Wv, Wo, We,
                                             xbf, wqb, wkb, wvb, wob, wet);
    proj_mfma_kernel<<<dim3(4, 64, 3), 256, 0, stream>>>(xbf, wqb, wkb, wvb,
                                                         qw, kw, vtg,
                                                         0.125f * 1.44269504089f);
    attn_v13_kernel<<<1024, 256, 0, stream>>>(qw, kw, vtg, wet, awb);
    out_mfma_kernel<<<dim3(8, 64), 256, 0, stream>>>(awb, wob, bo, (float*)d_out);
}

// Round 10
// 161.701 us; speedup vs baseline: 1.1671x; 1.0056x over previous
//
#include <hip/hip_runtime.h>

#define Lc 1024
#define Dc 512
#define Hc 8
#define DHc 64

typedef __attribute__((ext_vector_type(8))) short bf16x8;
typedef __attribute__((ext_vector_type(4))) float f32x4;
typedef __attribute__((ext_vector_type(16))) float f32x16;

typedef __attribute__((address_space(1))) const unsigned int guint;
typedef __attribute__((address_space(3))) unsigned int luint;

__device__ __forceinline__ void gload_lds16(const void* g, void* l) {
    __builtin_amdgcn_global_load_lds((guint*)g, (luint*)l, 16, 0, 0);
}

__device__ __forceinline__ unsigned short f2bf(float f) {
    unsigned u = __float_as_uint(f);
    u += 0x7fffu + ((u >> 16) & 1u);          // round-to-nearest-even
    return (unsigned short)(u >> 16);
}
__device__ __forceinline__ unsigned pk2(float a, float b) {
    return (unsigned)f2bf(a) | ((unsigned)f2bf(b) << 16);
}
__device__ __forceinline__ unsigned pk2t(float a, float b) {   // truncating pack, 1 v_perm
    return __builtin_amdgcn_perm(__float_as_uint(b), __float_as_uint(a), 0x07060302u);
}
__device__ __forceinline__ float bf2f(unsigned short s) { return __uint_as_float(((unsigned)s) << 16); }

// v_permlane32_swap_b32: a' = {a.lo, b.lo}; b' = {a.hi, b.hi}
__device__ __forceinline__ void pl32swap(unsigned &a, unsigned &b) {
    asm volatile("v_permlane32_swap_b32 %0, %1" : "+v"(a), "+v"(b));
}
// ({hi:lo} >> sh)[31:0], sh may be per-lane VGPR
__device__ __forceinline__ unsigned alignbit(unsigned hi, unsigned lo, unsigned sh) {
    unsigned d;
    asm("v_alignbit_b32 %0, %1, %2, %3" : "=v"(d) : "v"(hi), "v"(lo), "v"(sh));
    return d;
}

// ---------------------------------------------------------------------------
// fp32 -> bf16 cast of x, Wq, Wk, Wv, Wo, We.
// ---------------------------------------------------------------------------
__global__ void cvt_all_kernel(
    const float* __restrict__ x,  const float* __restrict__ Wq,
    const float* __restrict__ Wk, const float* __restrict__ Wv,
    const float* __restrict__ Wo, const float* __restrict__ We,
    unsigned short* __restrict__ xb,  unsigned short* __restrict__ wqb,
    unsigned short* __restrict__ wkb, unsigned short* __restrict__ wvb,
    unsigned short* __restrict__ wob, unsigned short* __restrict__ wet)
{
    int bid = blockIdx.x;
    const float* src; unsigned short* dst; size_t base;
    if      (bid < 2048) { src = x;  dst = xb;  base = (size_t)bid * 2048; }
    else if (bid < 2176) { src = Wq; dst = wqb; base = (size_t)(bid-2048) * 2048; }
    else if (bid < 2304) { src = Wk; dst = wkb; base = (size_t)(bid-2176) * 2048; }
    else if (bid < 2432) { src = Wv; dst = wvb; base = (size_t)(bid-2304) * 2048; }
    else if (bid < 2560) { src = Wo; dst = wob; base = (size_t)(bid-2432) * 2048; }
    else                 { src = We; dst = wet; base = (size_t)(bid-2560) * 2048; }
    size_t i = base + (size_t)threadIdx.x * 8;
    float4 a = *(const float4*)&src[i];
    float4 b = *(const float4*)&src[i + 4];
    uint4 o = make_uint4(pk2(a.x, a.y), pk2(a.z, a.w), pk2(b.x, b.y), pk2(b.z, b.w));
    *(uint4*)&dst[i] = o;
}

// ---------------------------------------------------------------------------
// proj v14: FUSED q/k/v projection. One block computes all three outputs for
// its (m0, n0) tile, sharing the A (x) staging and A-fragment reads:
//  - 128(m) x 64(n) tile, 2x2 wave grid (wm 64, wn 32), acc[3][4][2] (96 VGPR)
//  - per K-step: A staged/read ONCE (4 DMA + 8 b128/wave) + 3 B's (6 DMA +
//    12 b128/wave) = 20 b128/wave vs 36 for three separate launches (-44%)
//  - xb global traffic 25 MB -> 8.4 MB
//  - n0 spans exactly one head (N-tile 64 = DHc); epilogues carried over:
//    q/k quad-contiguous scalar stores, v LDS-transpose -> V^T (B,H,DH,L)
// ---------------------------------------------------------------------------
__global__ __launch_bounds__(256, 2) void proj_fused_kernel(
    const unsigned short* __restrict__ xb,
    const unsigned short* __restrict__ wq, const unsigned short* __restrict__ wk,
    const unsigned short* __restrict__ wv,
    unsigned short* __restrict__ qo, unsigned short* __restrict__ ko,
    unsigned short* __restrict__ vtg, float qscale)
{
    __shared__ unsigned short smem[20480];          // 40960 B
    unsigned short* As = smem;                      // 16 KB [128][64]
    unsigned short* Bs0 = smem + 8192;              // 8 KB  [64][64]
    unsigned short* Bs1 = smem + 12288;             // 8 KB
    unsigned short* Bs2 = smem + 16384;             // 8 KB

    const int t = threadIdx.x;
    const int lane = t & 63, w = t >> 6;
    const int lq = lane >> 4, ln = lane & 15;
    const int m0 = blockIdx.y * 128, n0 = blockIdx.x * 64;
    const int wm = (w & 1) * 64, wn = (w >> 1) * 32;
    const int srow = t >> 3;                        // 0..31
    const int lsg  = ((t & 7) ^ ((t >> 3) & 7)) * 8;
    const int key  = ln & 7;

    f32x4 acc[3][4][2];
    #pragma unroll
    for (int z = 0; z < 3; z++)
        #pragma unroll
        for (int i = 0; i < 4; i++)
            #pragma unroll
            for (int j = 0; j < 2; j++) acc[z][i][j] = (f32x4){0.f,0.f,0.f,0.f};

    for (int c0 = 0; c0 < 512; c0 += 64) {
        __syncthreads();
        #pragma unroll
        for (int g = 0; g < 4; g++)
            gload_lds16(&xb[(size_t)(m0 + 32*g + srow) * 512 + c0 + lsg], &As[(32*g + srow)*64 + (t&7)*8]);
        #pragma unroll
        for (int g = 0; g < 2; g++) {
            gload_lds16(&wq[(size_t)(n0 + 32*g + srow) * 512 + c0 + lsg], &Bs0[(32*g + srow)*64 + (t&7)*8]);
            gload_lds16(&wk[(size_t)(n0 + 32*g + srow) * 512 + c0 + lsg], &Bs1[(32*g + srow)*64 + (t&7)*8]);
            gload_lds16(&wv[(size_t)(n0 + 32*g + srow) * 512 + c0 + lsg], &Bs2[(32*g + srow)*64 + (t&7)*8]);
        }
        __syncthreads();

        #pragma unroll
        for (int kk = 0; kk < 2; kk++) {
            bf16x8 af[4];
            #pragma unroll
            for (int i = 0; i < 4; i++)
                af[i] = *(bf16x8*)&As[(wm + 16*i + ln)*64 + ((kk*4 + lq) ^ key)*8];

            unsigned short* Bz[3] = {Bs0, Bs1, Bs2};
            #pragma unroll
            for (int z = 0; z < 3; z++) {
                bf16x8 bf[2];
                #pragma unroll
                for (int j = 0; j < 2; j++)
                    bf[j] = *(bf16x8*)&Bz[z][(wn + 16*j + ln)*64 + ((kk*4 + lq) ^ key)*8];
                #pragma unroll
                for (int i = 0; i < 4; i++)
                    #pragma unroll
                    for (int j = 0; j < 2; j++)
                        acc[z][i][j] = __builtin_amdgcn_mfma_f32_16x16x32_bf16(af[i], bf[j], acc[z][i][j], 0, 0, 0);
            }
        }
    }

    const int h = n0 >> 6;                          // one head per n-tile

    // ---- q / k epilogues: quad-contiguous scalar stores ----
    #pragma unroll
    for (int z = 0; z < 2; z++) {
        unsigned short* out = z ? ko : qo;
        const float osc = z ? 1.0f : qscale;
        #pragma unroll
        for (int i = 0; i < 4; i++) {
            #pragma unroll
            for (int r = 0; r < 4; r++) {
                int m = m0 + wm + 16*i + 4*lq + r;
                int b = m >> 10, l = m & 1023;
                #pragma unroll
                for (int j = 0; j < 2; j++) {
                    int dh = wn + 16*j + ln;
                    out[((size_t)((b*Hc + h)*Lc + l))*DHc + dh] = f2bf(acc[z][i][j][r] * osc);
                }
            }
        }
    }

    // ---- v epilogue: transpose through LDS, write V^T (B,H,DH,L) ----
    __syncthreads();
    unsigned short* Ts = smem;                      // [64 n][136] = 17408 B
    #pragma unroll
    for (int i = 0; i < 4; i++) {
        int mlb = wm + 16*i + 4*lq;
        #pragma unroll
        for (int j = 0; j < 2; j++) {
            int nl = wn + 16*j + ln;
            *(uint2*)&Ts[nl*136 + mlb] = make_uint2(pk2(acc[2][i][j][0], acc[2][i][j][1]),
                                                    pk2(acc[2][i][j][2], acc[2][i][j][3]));
        }
    }
    __syncthreads();
    {
        const int b = m0 >> 10, l0m = m0 & 1023;
        const int nl = t >> 2, seg = (t & 3) * 32;
        unsigned short* dst = vtg + (((size_t)(b*Hc + h))*DHc + nl)*Lc + l0m + seg;
        #pragma unroll
        for (int u = 0; u < 4; u++)
            *(uint4*)&dst[8*u] = *(uint4*)&Ts[nl*136 + seg + 8*u];
    }
}

// ---------------------------------------------------------------------------
// Output GEMM: 128x64 tiles, 512 blocks = 2/CU (unchanged from R8).
// ---------------------------------------------------------------------------
__global__ __launch_bounds__(256, 2) void out_mfma_kernel(
    const unsigned short* __restrict__ A, const unsigned short* __restrict__ W,
    const float* __restrict__ bias, float* __restrict__ out)
{
    __shared__ unsigned short As[128 * 64];         // 16 KB
    __shared__ unsigned short Bs[64 * 64];          // 8 KB

    const int t = threadIdx.x;
    const int lane = t & 63, w = t >> 6;
    const int lq = lane >> 4, ln = lane & 15;
    const int m0 = blockIdx.y * 128, n0 = blockIdx.x * 64;
    const int wm = (w & 1) * 64, wn = (w >> 1) * 32;
    const int srow = t >> 3;                        // 0..31
    const int lsg  = ((t & 7) ^ ((t >> 3) & 7)) * 8;
    const int key  = ln & 7;

    f32x4 acc[4][2];
    #pragma unroll
    for (int i = 0; i < 4; i++)
        #pragma unroll
        for (int j = 0; j < 2; j++) acc[i][j] = (f32x4){0.f,0.f,0.f,0.f};

    for (int c0 = 0; c0 < 512; c0 += 64) {
        __syncthreads();
        #pragma unroll
        for (int g = 0; g < 4; g++)
            gload_lds16(&A[(size_t)(m0 + 32*g + srow) * 512 + c0 + lsg], &As[(32*g + srow)*64 + (t&7)*8]);
        #pragma unroll
        for (int g = 0; g < 2; g++)
            gload_lds16(&W[(size_t)(n0 + 32*g + srow) * 512 + c0 + lsg], &Bs[(32*g + srow)*64 + (t&7)*8]);
        __syncthreads();

        #pragma unroll
        for (int kk = 0; kk < 2; kk++) {
            bf16x8 af[4], bf[2];
            #pragma unroll
            for (int i = 0; i < 4; i++)
                af[i] = *(bf16x8*)&As[(wm + 16*i + ln)*64 + ((kk*4 + lq) ^ key)*8];
            #pragma unroll
            for (int j = 0; j < 2; j++)
                bf[j] = *(bf16x8*)&Bs[(wn + 16*j + ln)*64 + ((kk*4 + lq) ^ key)*8];
            #pragma unroll
            for (int i = 0; i < 4; i++)
                #pragma unroll
                for (int j = 0; j < 2; j++)
                    acc[i][j] = __builtin_amdgcn_mfma_f32_16x16x32_bf16(af[i], bf[j], acc[i][j], 0, 0, 0);
        }
    }

    float bb[2];
    #pragma unroll
    for (int j = 0; j < 2; j++) bb[j] = bias[n0 + wn + 16*j + ln];

    #pragma unroll
    for (int i = 0; i < 4; i++) {
        #pragma unroll
        for (int r = 0; r < 4; r++) {
            int m = m0 + wm + 16*i + 4*lq + r;
            #pragma unroll
            for (int j = 0; j < 2; j++) {
                int n = n0 + wn + 16*j + ln;
                out[(size_t)m * Dc + n] = acc[i][j][r] + bb[j];
            }
        }
    }
}

// ---------------------------------------------------------------------------
// attn v13 (UNCHANGED from R9 — control group this round).
// ---------------------------------------------------------------------------
__global__ __launch_bounds__(256, 4) void attn_v13_kernel(
    const unsigned short* __restrict__ q, const unsigned short* __restrict__ k,
    const unsigned short* __restrict__ vtg, const unsigned short* __restrict__ wet,
    unsigned short* __restrict__ attn)
{
    __shared__ unsigned short smem[20480];          // 40960 B total
    unsigned short* ksp  = smem;                    // 8192 B  K     [s][dh swz]
    unsigned short* vtp  = smem + 4096;             // 8192 B  V^T   [dh][s swz]  (prologue: We pb0)
    unsigned short* wesp = smem + 8192;             // 8192 B  We    [e][dh swz]  (1 iter ahead)
    unsigned short* qes  = smem + 12288;            // 16384 B QE ring TRANSPOSED [l][slot^swz]

    const int t    = threadIdx.x;
    const int lane = t & 63, w = t >> 6;
    const int ln31 = lane & 31, hi = lane >> 5;
    const int si   = w >> 1;                        // s / e half: 0/1
    const int li   = w & 1;                         // l half: 0/1

    const int n   = blockIdx.x;
    const int xcd = n & 7, idx = n >> 3;
    const int bh  = xcd * 8 + (idx >> 4);
    const int l0  = (idx & 15) * 64;

    const unsigned short* qb  = q   + (size_t)bh * (Lc * DHc);
    const unsigned short* kb  = k   + (size_t)bh * (Lc * DHc);
    const unsigned short* vtb = vtg + (size_t)bh * (DHc * Lc);

    const int srow2 = t >> 3;                       // 0..31 staging row
    const int lsg2  = ((t & 7) ^ ((t >> 3) & 7)) * 8;
    const int k7    = ln31 & 7;
    const int lloc  = 32*li + ln31;
    const int wkey  = (lloc & 15) << 2;             // ring col swizzle (bits 2-5)
    unsigned short* qrow = &qes[lloc * 128];

    // Q fragments (serve both A and B operand slots): Q[l][dh=16kk+8hi+j]
    bf16x8 qf[4];
    #pragma unroll
    for (int kk = 0; kk < 4; kk++)
        qf[kk] = *(const bf16x8*)&qb[(size_t)(l0 + lloc)*64 + kk*16 + hi*8];

    const int pb0 = 15 - (l0 >> 6);

    // prologue staging: panel pb0 -> vtp (scratch, pre-loop QE only),
    // panel pb0+1 (= newp of iter 0) -> wesp, K tile 0 -> ksp
    gload_lds16(&wet[(size_t)(64*pb0 + srow2)*64 + lsg2],        &vtp [t*8]);
    gload_lds16(&wet[(size_t)(64*pb0 + 32 + srow2)*64 + lsg2],   &vtp [2048 + t*8]);
    gload_lds16(&wet[(size_t)(64*(pb0+1) + srow2)*64 + lsg2],    &wesp[t*8]);
    gload_lds16(&wet[(size_t)(64*(pb0+1) + 32 + srow2)*64 + lsg2], &wesp[2048 + t*8]);
    gload_lds16(&kb [(size_t)srow2*64 + lsg2],                   &ksp [t*8]);
    gload_lds16(&kb [(size_t)(32 + srow2)*64 + lsg2],            &ksp [2048 + t*8]);
    __syncthreads();

    // pre-loop QE panel pb0 (from vtp scratch) -> transposed ring
    {
        f32x16 qec = (f32x16){0.f,0.f,0.f,0.f,0.f,0.f,0.f,0.f,0.f,0.f,0.f,0.f,0.f,0.f,0.f,0.f};
        #pragma unroll
        for (int kk = 0; kk < 4; kk++) {
            bf16x8 wf = *(bf16x8*)&vtp[(32*si + ln31)*64 + ((2*kk + hi) ^ k7)*8];
            qec = __builtin_amdgcn_mfma_f32_32x32x16_bf16(wf, qf[kk], qec, 0, 0, 0);
        }
        const int cb = (pb0 & 1) * 64;
        #pragma unroll
        for (int g = 0; g < 4; g++) {
            const int col = (cb + 32*si + 8*g + 4*hi) ^ wkey;
            *(uint2*)&qrow[col] = make_uint2(pk2(qec[4*g], qec[4*g+1]),
                                             pk2(qec[4*g+2], qec[4*g+3]));
        }
    }

    f32x16 Ov[2];
    #pragma unroll
    for (int dt = 0; dt < 2; dt++)
        Ov[dt] = (f32x16){0.f,0.f,0.f,0.f,0.f,0.f,0.f,0.f,0.f,0.f,0.f,0.f,0.f,0.f,0.f,0.f};
    float Lacc = 0.f;

    int pbOld = pb0 - 1;

    #pragma unroll 1
    for (int s0 = 0; s0 < Lc; s0 += 64) {
        const int c0  = l0 - s0;
        const int ac0 = c0 < 0 ? -c0 : c0;
        const int pb  = (960 - ac0) >> 6;
        const int newp = (pb > pbOld) ? pb + 1 : pb;
        pbOld = pb;
        const int cb = (newp & 1) * 64;
        const bool more = (s0 < Lc - 64);
        const int nc  = c0 - 64;
        const int nac = nc < 0 ? -nc : nc;
        const int npb = (960 - nac) >> 6;
        const int nnp = (npb > pb) ? npb + 1 : npb;   // newp of iter i+1

        __syncthreads();                            // B1: prev PV done; ring writable; ksp(i) drained

        // vtp(i): drains at B2 under the QE phase; consumed at PV
        gload_lds16(&vtb[(size_t)srow2*1024 + s0 + lsg2],        &vtp[t*8]);
        gload_lds16(&vtb[(size_t)(32 + srow2)*1024 + s0 + lsg2], &vtp[2048 + t*8]);

        // ---- QE: panel newp from wesp -> transposed ring ----
        {
            f32x16 qec = (f32x16){0.f,0.f,0.f,0.f,0.f,0.f,0.f,0.f,0.f,0.f,0.f,0.f,0.f,0.f,0.f,0.f};
            #pragma unroll
            for (int kk = 0; kk < 4; kk++) {
                bf16x8 wf = *(bf16x8*)&wesp[(32*si + ln31)*64 + ((2*kk + hi) ^ k7)*8];
                qec = __builtin_amdgcn_mfma_f32_32x32x16_bf16(wf, qf[kk], qec, 0, 0, 0);
            }
            #pragma unroll
            for (int g = 0; g < 4; g++) {
                const int col = (cb + 32*si + 8*g + 4*hi) ^ wkey;
                *(uint2*)&qrow[col] = make_uint2(pk2(qec[4*g], qec[4*g+1]),
                                                 pk2(qec[4*g+2], qec[4*g+3]));
            }
        }

        __syncthreads();                            // B2: ring visible; vtp drained; wesp free

        // wesp(i+1): drains at B3 under the QK+bias phase
        if (more) {
            gload_lds16(&wet[(size_t)(64*nnp + srow2)*64 + lsg2],      &wesp[t*8]);
            gload_lds16(&wet[(size_t)(64*nnp + 32 + srow2)*64 + lsg2], &wesp[2048 + t*8]);
        }

        // ---- S^T = mfma(K, Q): rows s = (reg&3)+8(reg>>2)+4hi + 32si, col l = lloc
        f32x16 sc = (f32x16){0.f,0.f,0.f,0.f,0.f,0.f,0.f,0.f,0.f,0.f,0.f,0.f,0.f,0.f,0.f,0.f};
        #pragma unroll
        for (int kk = 0; kk < 4; kk++) {
            bf16x8 kf = *(bf16x8*)&ksp[(32*si + ln31)*64 + ((2*kk + hi) ^ k7)*8];
            sc = __builtin_amdgcn_mfma_f32_32x32x16_bf16(kf, qf[kk], sc, 0, 0, 0);
        }

        // ---- bias gather + exp2 ----
        float p[16];
        if (c0 >= 128 || c0 <= -64) {
            const bool asc = (c0 >= 128);
            #pragma unroll
            for (int g = 0; g < 4; g++) {
                const int dbase0 = c0 + lloc - (32*si + 8*g + 4*hi);
                const int base = asc ? (1023 - dbase0) : (1020 + dbase0);
                const int a  = (base & ~3) & 127;
                const int a2 = (a + 4) & 127;
                const uint2 w01 = *(const uint2*)&qrow[a  ^ wkey];   // q0..q3
                const uint2 w23 = *(const uint2*)&qrow[a2 ^ wkey];   // q4..q7
                const int off = base & 3;
                const bool oh = (off >= 2);
                const unsigned wl = oh ? w01.y : w01.x;
                const unsigned wm = oh ? w23.x : w01.y;
                const unsigned wh = oh ? w23.y : w23.x;
                const unsigned sh = (unsigned)(off & 1) * 16u;
                const unsigned r0 = alignbit(wm, wl, sh);            // q_off, q_off+1
                const unsigned r1 = alignbit(wh, wm, sh);            // q_off+2, q_off+3
                float b0, b1, b2, b3;
                if (asc) {
                    b0 = __uint_as_float(r0 << 16);
                    b1 = __uint_as_float(r0 & 0xffff0000u);
                    b2 = __uint_as_float(r1 << 16);
                    b3 = __uint_as_float(r1 & 0xffff0000u);
                } else {                                             // reversed
                    b0 = __uint_as_float(r1 & 0xffff0000u);
                    b1 = __uint_as_float(r1 << 16);
                    b2 = __uint_as_float(r0 & 0xffff0000u);
                    b3 = __uint_as_float(r0 << 16);
                }
                p[4*g+0] = __builtin_amdgcn_exp2f(sc[4*g+0] + b0);
                p[4*g+1] = __builtin_amdgcn_exp2f(sc[4*g+1] + b1);
                p[4*g+2] = __builtin_amdgcn_exp2f(sc[4*g+2] + b2);
                p[4*g+3] = __builtin_amdgcn_exp2f(sc[4*g+3] + b3);
            }
        } else {                                    // c0 in {0, 64}: scalar fallback
            #pragma unroll
            for (int g = 0; g < 4; g++) {
                const int sb = 32*si + 8*g + 4*hi;
                #pragma unroll
                for (int r = 0; r < 4; r++) {
                    int d  = c0 + lloc - sb - r;
                    int ad = d < 0 ? -d : d;
                    int m  = 1023 - ad;
                    float bias = bf2f(qrow[(m & 127) ^ wkey]);
                    p[4*g + r] = __builtin_amdgcn_exp2f(sc[4*g + r] + bias);
                }
            }
        }

        // Lacc partial (this lane's 16 s-rows for its l)
        {
            float t0 = (p[0]+p[1]) + (p[2]+p[3]);
            float t1 = (p[4]+p[5]) + (p[6]+p[7]);
            float t2 = (p[8]+p[9]) + (p[10]+p[11]);
            float t3 = (p[12]+p[13]) + (p[14]+p[15]);
            Lacc += (t0 + t1) + (t2 + t3);
        }
        unsigned d0[4], d1[4];
        #pragma unroll
        for (int g = 0; g < 4; g++) {
            d0[g] = pk2t(p[4*g],     p[4*g + 1]);
            d1[g] = pk2t(p[4*g + 2], p[4*g + 3]);
        }
        bf16x8 pfr[2];
        #pragma unroll
        for (int kk = 0; kk < 2; kk++) {
            pl32swap(d0[2*kk], d0[2*kk + 1]);
            pl32swap(d1[2*kk], d1[2*kk + 1]);
            uint4 fu = make_uint4(d0[2*kk], d1[2*kk], d0[2*kk + 1], d1[2*kk + 1]);
            pfr[kk] = *(bf16x8*)&fu;
        }

        __syncthreads();                            // B3: ksp free; ring reads done; wesp(i+1) drained

        // ksp(i+1): drains at next B1 under the PV phase
        if (more) {
            gload_lds16(&kb[(size_t)(s0 + 64 + srow2)*64 + lsg2],      &ksp[t*8]);
            gload_lds16(&kb[(size_t)(s0 + 64 + 32 + srow2)*64 + lsg2], &ksp[2048 + t*8]);
        }

        // ---- O^T += mfma(V^T, P^T) over this wave's s-half ----
        #pragma unroll
        for (int kk = 0; kk < 2; kk++)
            #pragma unroll
            for (int dt = 0; dt < 2; dt++) {
                bf16x8 vf = *(bf16x8*)&vtp[(32*dt + ln31)*64 + (((4*si + 2*kk + hi) ^ k7))*8];
                Ov[dt] = __builtin_amdgcn_mfma_f32_32x32x16_bf16(vf, pfr[kk], Ov[dt], 0, 0, 0);
            }
    }

    // ---- epilogue: hi-merge Lacc, cross-si reduce via LDS, normalize, store
    unsigned la = __float_as_uint(Lacc), lb = la;
    pl32swap(la, lb);
    float Lh = Lacc + __uint_as_float(hi ? la : lb);   // full si-half denominator

    __syncthreads();
    float* scr = (float*)smem;                       // 33*128 f32 = 16.9 KB
    if (si == 1) {
        #pragma unroll
        for (int dt = 0; dt < 2; dt++)
            #pragma unroll
            for (int rg = 0; rg < 16; rg++)
                scr[(dt*16 + rg)*128 + li*64 + lane] = Ov[dt][rg];
        scr[32*128 + li*64 + lane] = Lh;
    }
    __syncthreads();
    if (si == 0) {
        const float Lt = Lh + scr[32*128 + li*64 + lane];
        const float inv = 1.f / Lt;
        const int b = bh >> 3, h = bh & 7;
        const int lg = l0 + lloc;
        unsigned short* dst = attn + ((size_t)(b*Lc + lg))*Dc + h*DHc;
        #pragma unroll
        for (int dt = 0; dt < 2; dt++)
            #pragma unroll
            for (int g = 0; g < 4; g++) {
                float v0 = (Ov[dt][4*g]   + scr[(dt*16 + 4*g)*128 + li*64 + lane]) * inv;
                float v1 = (Ov[dt][4*g+1] + scr[(dt*16 + 4*g+1)*128 + li*64 + lane]) * inv;
                float v2 = (Ov[dt][4*g+2] + scr[(dt*16 + 4*g+2)*128 + li*64 + lane]) * inv;
                float v3 = (Ov[dt][4*g+3] + scr[(dt*16 + 4*g+3)*128 + li*64 + lane]) * inv;
                *(uint2*)&dst[32*dt + 8*g + 4*hi] = make_uint2(pk2(v0, v1), pk2(v2, v3));
            }
    }
}

extern "C" void kernel_launch(void* const* d_in, const int* in_sizes, int n_in,
                              void* d_out, int out_size, void* d_ws, size_t ws_size,
                              hipStream_t stream)
{
    (void)in_sizes; (void)n_in; (void)out_size; (void)ws_size;
    const float* x  = (const float*)d_in[0];
    const float* Wq = (const float*)d_in[1];
    const float* Wk = (const float*)d_in[2];
    const float* Wv = (const float*)d_in[3];
    const float* We = (const float*)d_in[4];
    const float* Wo = (const float*)d_in[5];
    const float* bo = (const float*)d_in[6];

    const size_t NT = (size_t)8 * Hc * Lc * DHc;     // 4,194,304 elems
    unsigned short* qw  = (unsigned short*)d_ws;
    unsigned short* kw  = qw  + NT;
    unsigned short* vtg = kw  + NT;                  // V^T (B,H,DH,L)
    unsigned short* xbf = vtg + NT;
    unsigned short* awb = xbf + NT;                  // attn out bf16 (B,L,D)
    unsigned short* wqb = awb + NT;
    unsigned short* wkb = wqb + 262144;
    unsigned short* wvb = wkb + 262144;
    unsigned short* wob = wvb + 262144;
    unsigned short* wet = wob + 262144;              // 65536 + 4096 pad (panel-16 DMA overread)

    cvt_all_kernel<<<2592, 256, 0, stream>>>(x, Wq, Wk, Wv, Wo, We,
                                             xbf, wqb, wkb, wvb, wob, wet);
    proj_fused_kernel<<<dim3(8, 64), 256, 0, stream>>>(xbf, wqb, wkb, wvb,
                                                       qw, kw, vtg,
                                                       0.125f * 1.44269504089f);
    attn_v13_kernel<<<1024, 256, 0, stream>>>(qw, kw, vtg, wet, awb);
    out_mfma_kernel<<<dim3(8, 64), 256, 0, stream>>>(awb, wob, bo, (float*)d_out);
}